// Round 5
// baseline (18575.653 us; speedup 1.0000x reference)
//
#include <hip/hip_runtime.h>
#include <hip/hip_cooperative_groups.h>
#include <cstdio>

namespace cg = cooperative_groups;

#define BB 4
#define TT 12
#define CC 64
#define NN 10000
#define HH 64
#define LL 2
#define NEDGE 2000
#define NNZT 80000
#define KTOP 10
#define DEMB 16
#define BT (BB*TT)
#define SGRID 626          // 2*626 = 1252 = 313*4 zr/hy tasks exactly
#define SMEM_BYTES 37504   // in_t/in2:17408 | hn:8320 | yt:9216 | tki:1280 | tkw:1280

typedef long long ll;
typedef unsigned long long u64;

__device__ __forceinline__ float4 f4z() { return make_float4(0.f,0.f,0.f,0.f); }
__device__ __forceinline__ void f4add(float4& a, const float4 b){ a.x+=b.x; a.y+=b.y; a.z+=b.z; a.w+=b.w; }
__device__ __forceinline__ void f4fma(float4& a, float w, const float4 b){ a.x+=w*b.x; a.y+=w*b.y; a.z+=w*b.z; a.w+=w*b.w; }

// ---------------- graph setup ----------------
__global__ void deg_kernel(const int* __restrict__ nidx, const int* __restrict__ eidx,
                           int* __restrict__ ndeg, int* __restrict__ edeg) {
  int i = blockIdx.x*256 + threadIdx.x;
  if (i < NNZT) { atomicAdd(&ndeg[nidx[i]],1); atomicAdd(&edeg[eidx[i]],1); }
}

__global__ void exscan_kernel(const int* __restrict__ cnt, int* __restrict__ off, int n) {
  __shared__ int part[256];
  int tid = threadIdx.x;
  int chunk = (n + 255)/256;
  int lo = tid*chunk, hi = min(lo+chunk, n);
  int s = 0;
  for (int i=lo; i<hi; ++i) s += cnt[i];
  part[tid]=s; __syncthreads();
  if (tid==0){ int acc=0; for(int i=0;i<256;++i){int v=part[i];part[i]=acc;acc+=v;} off[n]=acc; }
  __syncthreads();
  int acc = part[tid];
  for (int i=lo; i<hi; ++i){ off[i]=acc; acc+=cnt[i]; }
}

__global__ void fill_csr_kernel(const int* __restrict__ nidx, const int* __restrict__ eidx,
                                const int* __restrict__ noff, const int* __restrict__ eoff,
                                int* __restrict__ ncur, int* __restrict__ ecur,
                                int* __restrict__ node_edges, int* __restrict__ edge_nodes) {
  int i = blockIdx.x*256 + threadIdx.x;
  if (i >= NNZT) return;
  int n = nidx[i], e = eidx[i];
  int pn = atomicAdd(&ncur[n],1);
  node_edges[noff[n]+pn] = e;
  int pe = atomicAdd(&ecur[e],1);
  edge_nodes[eoff[e]+pe] = n;
}

__global__ void invdeg_kernel(const int* __restrict__ ndeg, const int* __restrict__ edeg,
                              float* __restrict__ inv_n, float* __restrict__ inv_e) {
  int i = blockIdx.x*256+threadIdx.x;
  if (i < NN) inv_n[i] = 1.0f/fmaxf((float)ndeg[i],1.0f);
  if (i < NEDGE) inv_e[i] = 1.0f/fmaxf((float)edeg[i],1.0f);
}

// ---------------- top-k: wave-uniform threshold + buffered bitonic reselect ----------------
__device__ __forceinline__ u64 sortstep(u64 X, int j, bool dir, int lane) {
  u64 p = __shfl_xor(X, j);
  bool lower = ((lane & j) == 0);
  bool keep_min = (dir == lower);
  bool xlt = (X < p);
  u64 mn = xlt ? X : p;
  u64 mx = xlt ? p : X;
  return keep_min ? mn : mx;
}

__device__ __forceinline__ void reselect(u64* bq, u64& thr, int& cnt, int lane) {
  int tot = 10 + cnt;                       // <= 113 < 128
  u64 A = (lane < tot)      ? bq[lane]      : 0ull;
  u64 B = (lane + 64 < tot) ? bq[lane + 64] : 0ull;
  for (int k = 2; k <= 32; k <<= 1) {
    for (int j = k >> 1; j >= 1; j >>= 1) {
      bool dir = ((lane & k) == 0);
      A = sortstep(A, j, dir, lane);
      B = sortstep(B, j, dir, lane);
    }
  }
  for (int j = 32; j >= 1; j >>= 1) {
    A = sortstep(A, j, true,  lane);
    B = sortstep(B, j, false, lane);
  }
  {
    bool lt = (A < B);
    u64 mn = lt ? A : B, mx = lt ? B : A;
    A = mn; B = mx;
  }
  for (int j = 32; j >= 1; j >>= 1) {
    A = sortstep(A, j, true, lane);
    B = sortstep(B, j, true, lane);
  }
  if (lane >= 54) bq[63 - lane] = B;
  thr = __shfl(B, 54);
  cnt = 0;
}

__global__ void __launch_bounds__(256) topk_kernel(const float* __restrict__ E,
                                                   int* __restrict__ tk_idx,
                                                   float* __restrict__ tk_w) {
  __shared__ u64 buf[16][128];
  int tid = threadIdx.x;
  int wv = tid >> 6, lane = tid & 63;
  int qbase = blockIdx.x*16 + wv*4;         // 625*16 = 10000 exactly
  const float4* E4 = (const float4*)E;
  float4 q[4][4];
  #pragma unroll
  for (int u=0;u<4;++u) {
    int n = qbase + u;
    #pragma unroll
    for (int j=0;j<4;++j) q[u][j] = E4[(ll)n*4 + j];
  }
  u64 thr[4] = {0,0,0,0};
  int cnt[4] = {0,0,0,0};
  buf[tid>>4][tid&15] = 0ull;               // each wave inits its own 4 rows
  for (int cb=0; cb<NN; cb+=64) {
    int cand = cb + lane;
    bool valid = (cand < NN);
    int ca = valid ? cand : 0;
    // coalesced: lane i reads 64 contiguous bytes of row (cb+i); wave covers 4KB
    float4 a0 = E4[(ll)ca*4], a1 = E4[(ll)ca*4+1], a2 = E4[(ll)ca*4+2], a3 = E4[(ll)ca*4+3];
    u64 low = (u64)(0x00FFFFFFu - (unsigned)cand);
    u64 key[4];
    #pragma unroll
    for (int u=0;u<4;++u) {
      float dot = q[u][0].x*a0.x + q[u][0].y*a0.y + q[u][0].z*a0.z + q[u][0].w*a0.w
                + q[u][1].x*a1.x + q[u][1].y*a1.y + q[u][1].z*a1.z + q[u][1].w*a1.w
                + q[u][2].x*a2.x + q[u][2].y*a2.y + q[u][2].z*a2.z + q[u][2].w*a2.w
                + q[u][3].x*a3.x + q[u][3].y*a3.y + q[u][3].z*a3.z + q[u][3].w*a3.w;
      float s = fmaxf(dot, 0.f);
      u64 kk = ((u64)__float_as_uint(s) << 32) | low;
      key[u] = valid ? kk : 0ull;
    }
    #pragma unroll
    for (int u=0;u<4;++u) {
      u64 mask = __ballot(key[u] > thr[u]);
      if (mask) {
        if (key[u] > thr[u]) {
          int myofs = (int)__popcll(mask & ((1ull<<lane)-1ull));
          buf[wv*4+u][10 + cnt[u] + myofs] = key[u];
        }
        cnt[u] += (int)__popcll(mask);
        if (cnt[u] >= 40) reselect(&buf[wv*4+u][0], thr[u], cnt[u], lane);
      }
    }
  }
  #pragma unroll
  for (int u=0;u<4;++u) {
    u64* bq = &buf[wv*4+u][0];
    if (cnt[u] > 0) reselect(bq, thr[u], cnt[u], lane);
    u64 k10 = (lane < 10) ? bq[lane] : 0ull;
    float v = __uint_as_float((unsigned)(k10 >> 32));
    int idx = 0x00FFFFFF - (int)(k10 & 0xFFFFFFFFull);
    float v0 = __shfl(v, 0);
    float e = (lane < 10) ? expf(v - v0) : 0.f;
    float s = e;
    for (int o=1;o<16;o<<=1) s += __shfl_xor(s, o);
    if (lane < 10) {
      int n = qbase + u;
      tk_w[n*KTOP + lane] = e / s;
      tk_idx[n*KTOP + lane] = idx;
    }
  }
}

// ---------------- (B,T,C,N) -> (B*T, N, C) transpose ----------------
__global__ void transpose_kernel(const float* __restrict__ src, float* __restrict__ dst) {
  __shared__ float tile[32][33];
  int bt = blockIdx.z;
  int n0 = blockIdx.x*32, c0 = blockIdx.y*32;
  for (int i=threadIdx.y; i<32; i+=8) {
    int c = c0+i, nn = n0+threadIdx.x;
    tile[i][threadIdx.x] = (nn<NN)? src[((ll)bt*CC + c)*NN + nn] : 0.0f;
  }
  __syncthreads();
  for (int i=threadIdx.y; i<32; i+=8) {
    int nn = n0+i, c = c0+threadIdx.x;
    if (nn<NN) dst[((ll)bt*NN+nn)*64 + c] = tile[threadIdx.x][i];
  }
}

// ================= shared phase bodies (used by standalone kernels AND scan) =================
__device__ __forceinline__ void edge_body(int tid, int eb, int s,
    const float4* __restrict__ f4, float4* __restrict__ eagg4,
    const int* __restrict__ eoff, const int* __restrict__ enodes,
    const float* __restrict__ inv_e) {
  int e = eb*16 + (tid>>4);
  int lane = tid & 15;
  if (e < NEDGE) {
    int j0 = eoff[e], j1 = eoff[e+1];
    const float4* fb = f4 + (ll)s*NN*16;
    float4 acc = f4z();
    int j = j0;
    for (; j+16 <= j1; j += 16) {
      int idx = enodes[j+lane];
      #pragma unroll
      for (int jj=0; jj<16; ++jj) {
        int node = __shfl(idx, (tid & 48) + jj, 64);
        f4add(acc, fb[(ll)node*16 + lane]);
      }
    }
    for (; j<j1; ++j) f4add(acc, fb[(ll)enodes[j]*16 + lane]);
    float sc = inv_e[e];
    acc.x*=sc; acc.y*=sc; acc.z*=sc; acc.w*=sc;
    eagg4[((ll)s*NEDGE+e)*16+lane] = acc;
  }
}

__device__ void zr_body(int tid, int n0, int b, int t, int hzero, char* smem,
    const float4* __restrict__ h4, const float4* __restrict__ cx4,
    const float4* __restrict__ eagg4,
    const float* __restrict__ Wz, const float* __restrict__ bz,
    const int* __restrict__ noff, const int* __restrict__ nedges,
    const float* __restrict__ inv_n,
    const int* __restrict__ tk_idx, const float* __restrict__ tk_w,
    const float* __restrict__ hs, float* __restrict__ rh, float* __restrict__ zout) {
  float (*in_t)[136] = (float(*)[136])smem;
  int   (*tki_s)[KTOP] = (int(*)[KTOP])(smem + 34944);
  float (*tkw_s)[KTOP] = (float(*)[KTOP])(smem + 36224);
  int bt = b*TT + t;
  for (int i=tid; i<32*KTOP; i+=256) {
    int r=i/KTOP, k=i%KTOP; int n=n0+r;
    tki_s[r][k] = (n<NN)? tk_idx[n*KTOP+k] : 0;
    tkw_s[r][k] = (n<NN)? tk_w[n*KTOP+k] : 0.f;
  }
  __syncthreads();
  #pragma unroll
  for (int kk=0;kk<2;++kk) {
    int slot = tid + kk*256;
    int row = slot>>4, lane = slot&15;
    int n = n0 + row;
    float4 cxv = f4z(), chv = f4z();
    if (n < NN) {
      cxv = cx4[((ll)bt*NN + n)*16 + lane];
      if (!hzero) {
        float4 stv = f4z();
        int j0 = noff[n], j1 = noff[n+1];
        const float4* eb = eagg4 + (ll)b*NEDGE*16;
        for (int j=j0;j<j1;++j) f4add(stv, eb[(ll)nedges[j]*16 + lane]);
        float sc = 0.5f*inv_n[n];
        float4 adv = f4z();
        const float4* hb = h4 + (ll)b*NN*16;
        #pragma unroll
        for (int k=0;k<KTOP;++k) f4fma(adv, tkw_s[row][k], hb[(ll)tki_s[row][k]*16 + lane]);
        chv.x = sc*stv.x + 0.5f*adv.x;
        chv.y = sc*stv.y + 0.5f*adv.y;
        chv.z = sc*stv.z + 0.5f*adv.z;
        chv.w = sc*stv.w + 0.5f*adv.w;
      }
    }
    *(float4*)&in_t[row][lane*4] = cxv;
    *(float4*)&in_t[row][64+lane*4] = chv;
  }
  __syncthreads();
  int col = tid & 127, rg = tid >> 7;
  float acc[16];
  float bias = bz[col];
  #pragma unroll
  for (int r=0;r<16;++r) acc[r]=bias;
  for (int i4=0;i4<32;++i4) {
    float w0 = Wz[(i4*4+0)*128+col];
    float w1 = Wz[(i4*4+1)*128+col];
    float w2 = Wz[(i4*4+2)*128+col];
    float w3 = Wz[(i4*4+3)*128+col];
    #pragma unroll
    for (int r=0;r<16;++r) {
      const float4 v = *(const float4*)&in_t[rg*16+r][i4*4];
      acc[r] += v.x*w0 + v.y*w1 + v.z*w2 + v.w*w3;
    }
  }
  #pragma unroll
  for (int r=0;r<16;++r) {
    int n = n0 + rg*16 + r;
    if (n < NN) {
      float v = 1.0f/(1.0f+expf(-acc[r]));
      if (col < 64) zout[((ll)b*NN+n)*64+col] = v;
      else {
        int c = col-64;
        float hv = hzero ? 0.f : hs[((ll)b*NN+n)*64+c];
        rh[((ll)b*NN+n)*64+c] = v*hv;
      }
    }
  }
  __syncthreads();
}

__device__ void hy_body(int tid, int n0, int b, int t, int hzero, char* smem,
    const float4* __restrict__ rh4, const float4* __restrict__ cx4,
    const float4* __restrict__ eagg4,
    const float* __restrict__ Wc, const float* __restrict__ bc,
    const float* __restrict__ Wo, const float* __restrict__ bo,
    const int* __restrict__ noff, const int* __restrict__ nedges,
    const float* __restrict__ inv_n,
    const int* __restrict__ tk_idx, const float* __restrict__ tk_w,
    const float* __restrict__ zbuf, float* __restrict__ h, float* __restrict__ out) {
  float (*in2)[136] = (float(*)[136])smem;
  float (*hn)[65]   = (float(*)[65])(smem + 17408);
  float (*yt)[36]   = (float(*)[36])(smem + 25728);
  int   (*tki_s)[KTOP] = (int(*)[KTOP])(smem + 34944);
  float (*tkw_s)[KTOP] = (float(*)[KTOP])(smem + 36224);
  int bt = b*TT + t;
  for (int i=tid; i<32*KTOP; i+=256) {
    int r=i/KTOP, k=i%KTOP; int n=n0+r;
    tki_s[r][k] = (n<NN)? tk_idx[n*KTOP+k] : 0;
    tkw_s[r][k] = (n<NN)? tk_w[n*KTOP+k] : 0.f;
  }
  __syncthreads();
  #pragma unroll
  for (int kk=0;kk<2;++kk) {
    int slot = tid + kk*256;
    int row = slot>>4, lane = slot&15;
    int n = n0 + row;
    float4 cxv = f4z(), chv = f4z();
    if (n < NN) {
      cxv = cx4[((ll)bt*NN + n)*16 + lane];
      if (!hzero) {
        float4 stv = f4z();
        int j0 = noff[n], j1 = noff[n+1];
        const float4* eb = eagg4 + (ll)b*NEDGE*16;
        for (int j=j0;j<j1;++j) f4add(stv, eb[(ll)nedges[j]*16 + lane]);
        float sc = 0.5f*inv_n[n];
        float4 adv = f4z();
        const float4* rb = rh4 + (ll)b*NN*16;
        #pragma unroll
        for (int k=0;k<KTOP;++k) f4fma(adv, tkw_s[row][k], rb[(ll)tki_s[row][k]*16 + lane]);
        chv.x = sc*stv.x + 0.5f*adv.x;
        chv.y = sc*stv.y + 0.5f*adv.y;
        chv.z = sc*stv.z + 0.5f*adv.z;
        chv.w = sc*stv.w + 0.5f*adv.w;
      }
    }
    *(float4*)&in2[row][lane*4] = cxv;
    *(float4*)&in2[row][64+lane*4] = chv;
  }
  __syncthreads();
  {
    int col = tid & 63, rg = tid >> 6;
    float acc[8];
    float bias = bc[col];
    #pragma unroll
    for (int r=0;r<8;++r) acc[r]=bias;
    for (int i4=0;i4<32;++i4) {
      float w0 = Wc[(i4*4+0)*64+col];
      float w1 = Wc[(i4*4+1)*64+col];
      float w2 = Wc[(i4*4+2)*64+col];
      float w3 = Wc[(i4*4+3)*64+col];
      #pragma unroll
      for (int r=0;r<8;++r) {
        const float4 v = *(const float4*)&in2[rg*8+r][i4*4];
        acc[r] += v.x*w0+v.y*w1+v.z*w2+v.w*w3;
      }
    }
    #pragma unroll
    for (int r=0;r<8;++r) {
      int row = rg*8+r; int n = n0+row;
      float hnew = 0.0f;
      if (n<NN) {
        float cval = tanhf(acc[r]);
        float z = zbuf[((ll)b*NN+n)*64+col];
        float hv = hzero ? 0.f : h[((ll)b*NN+n)*64+col];
        hnew = z*hv + (1.0f-z)*cval;
        h[((ll)b*NN+n)*64+col] = hnew;
      }
      hn[row][col] = hnew;
    }
  }
  __syncthreads();
  {
    int col = tid & 63, rg = tid >> 6;
    float acc[8];
    float bias = bo[col];
    #pragma unroll
    for (int r=0;r<8;++r) acc[r]=bias;
    for (int i4=0;i4<16;++i4) {
      float w0 = Wo[(i4*4+0)*64+col];
      float w1 = Wo[(i4*4+1)*64+col];
      float w2 = Wo[(i4*4+2)*64+col];
      float w3 = Wo[(i4*4+3)*64+col];
      #pragma unroll
      for (int r=0;r<8;++r) {
        float vx = hn[rg*8+r][i4*4+0];
        float vy = hn[rg*8+r][i4*4+1];
        float vz = hn[rg*8+r][i4*4+2];
        float vw = hn[rg*8+r][i4*4+3];
        acc[r] += vx*w0+vy*w1+vz*w2+vw*w3;
      }
    }
    #pragma unroll
    for (int r=0;r<8;++r) yt[col][rg*8+r] = acc[r];
  }
  __syncthreads();
  #pragma unroll
  for (int kk=0;kk<2;++kk) {
    int slot = tid + kk*256;
    int col = slot>>3, q = slot&7;
    int n = n0 + q*4;
    if (n < NN) {
      float4 y = *(const float4*)&yt[col][q*4];
      float4* dst = (float4*)&out[((ll)bt*64+col)*NN + n];
      float4 cur = *dst;
      cur.x += y.x; cur.y += y.y; cur.z += y.z; cur.w += y.w;
      *dst = cur;
    }
  }
  __syncthreads();
}

// ---------------- standalone wrappers (fallback path) ----------------
__global__ void __launch_bounds__(256) edge_agg_kernel(
    const float4* __restrict__ f4, float4* __restrict__ eagg4,
    const int* __restrict__ eoff, const int* __restrict__ enodes,
    const float* __restrict__ inv_e) {
  edge_body(threadIdx.x, blockIdx.x, blockIdx.y, f4, eagg4, eoff, enodes, inv_e);
}

__global__ void __launch_bounds__(256,3) step_zr_kernel(
    const float4* h4, const float4* cx4, const float4* eagg4,
    const float* Wz, const float* bz,
    const int* noff, const int* nedges, const float* inv_n,
    const int* tki, const float* tkw,
    const float* hs, float* rh, float* zout, int t, int hzero) {
  __shared__ __align__(16) char smem[SMEM_BYTES];
  zr_body(threadIdx.x, blockIdx.x*32, blockIdx.y, t, hzero, smem,
          h4, cx4, eagg4, Wz, bz, noff, nedges, inv_n, tki, tkw, hs, rh, zout);
}

__global__ void __launch_bounds__(256,3) step_hy_kernel(
    const float4* rh4, const float4* cx4, const float4* eagg4,
    const float* Wc, const float* bc, const float* Wo, const float* bo,
    const int* noff, const int* nedges, const float* inv_n,
    const int* tki, const float* tkw,
    const float* zbuf, float* h, float* out, int t, int hzero) {
  __shared__ __align__(16) char smem[SMEM_BYTES];
  hy_body(threadIdx.x, blockIdx.x*32, blockIdx.y, t, hzero, smem,
          rh4, cx4, eagg4, Wc, bc, Wo, bo, noff, nedges, inv_n, tki, tkw, zbuf, h, out);
}

// ---------------- cooperative whole-scan kernel (one launch per layer) ----------------
__global__ void __launch_bounds__(256,3) scan_kernel(
    const float4* __restrict__ cx4,
    const float* __restrict__ Wz, const float* __restrict__ bz,
    const float* __restrict__ Wc, const float* __restrict__ bc,
    const float* __restrict__ Wo, const float* __restrict__ bo,
    const int* __restrict__ noff, const int* __restrict__ nedges, const float* __restrict__ inv_n,
    const int* __restrict__ eoff, const int* __restrict__ enodes, const float* __restrict__ inv_e,
    const int* __restrict__ tki, const float* __restrict__ tkw,
    float* __restrict__ hbuf, float* __restrict__ rhbuf, float* __restrict__ zbuf,
    float* __restrict__ eaggh, float* __restrict__ out) {
  __shared__ __align__(16) char smem[SMEM_BYTES];
  cg::grid_group grid = cg::this_grid();
  int tid = threadIdx.x;
  int gsz = gridDim.x;
  for (int t=0; t<TT; ++t) {
    int hz = (t==0) ? 1 : 0;
    if (!hz) {
      for (int task = blockIdx.x; task < 500; task += gsz)
        edge_body(tid, task%125, task/125, (const float4*)hbuf, (float4*)eaggh,
                  eoff, enodes, inv_e);
      __threadfence();
      grid.sync();
    }
    for (int task = blockIdx.x; task < 1252; task += gsz)
      zr_body(tid, (task%313)*32, task/313, t, hz, smem,
              (const float4*)hbuf, cx4, (const float4*)eaggh, Wz, bz,
              noff, nedges, inv_n, tki, tkw, hbuf, rhbuf, zbuf);
    __threadfence();
    grid.sync();
    for (int task = blockIdx.x; task < 500; task += gsz)
      edge_body(tid, task%125, task/125, (const float4*)rhbuf, (float4*)eaggh,
                eoff, enodes, inv_e);
    __threadfence();
    grid.sync();
    for (int task = blockIdx.x; task < 1252; task += gsz)
      hy_body(tid, (task%313)*32, task/313, t, hz, smem,
              (const float4*)rhbuf, cx4, (const float4*)eaggh, Wc, bc, Wo, bo,
              noff, nedges, inv_n, tki, tkw, zbuf, hbuf, out);
    __threadfence();
    grid.sync();
  }
}

// ---------------- conv applied to x for all (b,t) (float4) ----------------
__global__ void __launch_bounds__(256) conv_x_kernel(
    const float4* __restrict__ xt4, const float4* __restrict__ eagg4,
    const int* __restrict__ noff, const int* __restrict__ nedges,
    const float* __restrict__ inv_n,
    const int* __restrict__ tk_idx, const float* __restrict__ tk_w,
    float4* __restrict__ cx4) {
  __shared__ int tki_s[16][KTOP];
  __shared__ float tkw_s[16][KTOP];
  int tid = threadIdx.x; int s = blockIdx.y; int n0 = blockIdx.x*16;
  for (int i=tid; i<16*KTOP; i+=256) {
    int r=i/KTOP, k=i%KTOP;
    tki_s[r][k] = tk_idx[(n0+r)*KTOP+k];
    tkw_s[r][k] = tk_w[(n0+r)*KTOP+k];
  }
  __syncthreads();
  int row = tid>>4, lane = tid&15;
  int n = n0 + row;
  float4 stv = f4z();
  int j0 = noff[n], j1 = noff[n+1];
  const float4* eb = eagg4 + (ll)s*NEDGE*16;
  for (int j=j0;j<j1;++j) f4add(stv, eb[(ll)nedges[j]*16 + lane]);
  float sc = 0.5f*inv_n[n];
  float4 adv = f4z();
  const float4* xb = xt4 + (ll)s*NN*16;
  #pragma unroll
  for (int k=0;k<KTOP;++k) f4fma(adv, tkw_s[row][k], xb[(ll)tki_s[row][k]*16 + lane]);
  float4 r;
  r.x = sc*stv.x + 0.5f*adv.x;
  r.y = sc*stv.y + 0.5f*adv.y;
  r.z = sc*stv.z + 0.5f*adv.z;
  r.w = sc*stv.w + 0.5f*adv.w;
  cx4[((ll)s*NN+n)*16+lane] = r;
}

extern "C" void kernel_launch(void* const* d_in, const int* in_sizes, int n_in,
                              void* d_out, int out_size, void* d_ws, size_t ws_size,
                              hipStream_t stream) {
  const float* x    = (const float*)d_in[0];
  const int*  hidx  = (const int*)d_in[1];
  const float* embs = (const float*)d_in[2];
  const float* W_zr = (const float*)d_in[3];
  const float* b_zr = (const float*)d_in[4];
  const float* W_c  = (const float*)d_in[5];
  const float* b_c  = (const float*)d_in[6];
  const float* W_out= (const float*)d_in[7];
  const float* b_out= (const float*)d_in[8];
  const int* node_idx = hidx;
  const int* edge_idx = hidx + NNZT;

  char* ws = (char*)d_ws;
  size_t off = 0;
  auto alloc = [&](size_t bytes) -> void* {
    void* p = ws + off; off += (bytes + 255) & ~(size_t)255; return p;
  };
  float* xt    = (float*)alloc((size_t)BT*NN*64*4);
  float* cx    = (float*)alloc((size_t)BT*NN*64*4);
  float* eaggx = (float*)alloc((size_t)BT*NEDGE*64*4);
  float* eaggh = (float*)alloc((size_t)BB*NEDGE*64*4);
  float* hbuf  = (float*)alloc((size_t)BB*NN*64*4);
  float* rhbuf = (float*)alloc((size_t)BB*NN*64*4);
  float* zbuf  = (float*)alloc((size_t)BB*NN*64*4);
  float* tkw   = (float*)alloc((size_t)NN*KTOP*4);
  float* inv_e = (float*)alloc(NEDGE*4);
  float* inv_n = (float*)alloc(NN*4);
  int* tki     = (int*)alloc((size_t)NN*KTOP*4);
  int* ndeg    = (int*)alloc(NN*4);
  int* edeg    = (int*)alloc(NEDGE*4);
  int* noff    = (int*)alloc((NN+1)*4);
  int* eoff    = (int*)alloc((NEDGE+1)*4);
  int* ncur    = (int*)alloc(NN*4);
  int* ecur    = (int*)alloc(NEDGE*4);
  int* nedges  = (int*)alloc(NNZT*4);
  int* enodes  = (int*)alloc(NNZT*4);
  if (off > ws_size) {
    fprintf(stderr, "kernel_launch: ws too small, need %zu have %zu\n", off, ws_size);
    return;
  }

  // out starts as x (residual base)
  hipMemcpyAsync(d_out, x, (size_t)BB*TT*CC*NN*4, hipMemcpyDeviceToDevice, stream);

  // graph structure (once)
  hipMemsetAsync(ndeg, 0, NN*4, stream);
  hipMemsetAsync(edeg, 0, NEDGE*4, stream);
  hipMemsetAsync(ncur, 0, NN*4, stream);
  hipMemsetAsync(ecur, 0, NEDGE*4, stream);
  deg_kernel<<<(NNZT+255)/256,256,0,stream>>>(node_idx, edge_idx, ndeg, edeg);
  exscan_kernel<<<1,256,0,stream>>>(ndeg, noff, NN);
  exscan_kernel<<<1,256,0,stream>>>(edeg, eoff, NEDGE);
  fill_csr_kernel<<<(NNZT+255)/256,256,0,stream>>>(node_idx, edge_idx, noff, eoff,
                                                   ncur, ecur, nedges, enodes);
  invdeg_kernel<<<(NN+255)/256,256,0,stream>>>(ndeg, edeg, inv_n, inv_e);

  float* outp = (float*)d_out;
  int nblk = (NN + 31)/32;  // 313
  for (int l=0; l<LL; ++l) {
    topk_kernel<<<625,256,0,stream>>>(embs + (size_t)l*NN*DEMB, tki, tkw);
    transpose_kernel<<<dim3((NN+31)/32, CC/32, BT), dim3(32,8), 0, stream>>>(outp, xt);
    edge_agg_kernel<<<dim3((NEDGE+15)/16, BT),256,0,stream>>>(
        (const float4*)xt, (float4*)eaggx, eoff, enodes, inv_e);
    conv_x_kernel<<<dim3(NN/16, BT),256,0,stream>>>(
        (const float4*)xt, (const float4*)eaggx, noff, nedges, inv_n, tki, tkw, (float4*)cx);
    const float* Wz = W_zr + (size_t)l*128*128; const float* bz = b_zr + l*128;
    const float* Wc = W_c  + (size_t)l*128*64;  const float* bc = b_c + l*64;
    const float* Wo = W_out+ (size_t)l*64*64;   const float* bo = b_out + l*64;

    // one cooperative launch covering all T steps of this layer
    const float4* cx4c = (const float4*)cx;
    void* sargs[] = {
      (void*)&cx4c, (void*)&Wz, (void*)&bz, (void*)&Wc, (void*)&bc, (void*)&Wo, (void*)&bo,
      (void*)&noff, (void*)&nedges, (void*)&inv_n,
      (void*)&eoff, (void*)&enodes, (void*)&inv_e,
      (void*)&tki, (void*)&tkw,
      (void*)&hbuf, (void*)&rhbuf, (void*)&zbuf, (void*)&eaggh, (void*)&outp
    };
    hipError_t ce = hipLaunchCooperativeKernel(reinterpret_cast<void*>(scan_kernel),
                                               dim3(SGRID), dim3(256), sargs, 0, stream);
    if (ce != hipSuccess) {
      (void)hipGetLastError();  // clear
      for (int t=0; t<TT; ++t) {
        int hz = (t==0) ? 1 : 0;
        if (!hz)
          edge_agg_kernel<<<dim3(125, BB),256,0,stream>>>(
              (const float4*)hbuf, (float4*)eaggh, eoff, enodes, inv_e);
        step_zr_kernel<<<dim3(nblk, BB),256,0,stream>>>(
            (const float4*)hbuf, (const float4*)cx, (const float4*)eaggh, Wz, bz,
            noff, nedges, inv_n, tki, tkw, hbuf, rhbuf, zbuf, t, hz);
        if (!hz)
          edge_agg_kernel<<<dim3(125, BB),256,0,stream>>>(
              (const float4*)rhbuf, (float4*)eaggh, eoff, enodes, inv_e);
        step_hy_kernel<<<dim3(nblk, BB),256,0,stream>>>(
            (const float4*)rhbuf, (const float4*)cx, (const float4*)eaggh, Wc, bc, Wo, bo,
            noff, nedges, inv_n, tki, tkw, zbuf, hbuf, outp, t, hz);
      }
    }
  }
}

// Round 6
// 5013.546 us; speedup vs baseline: 3.7051x; 3.7051x over previous
//
#include <hip/hip_runtime.h>
#include <cstdio>

#define BB 4
#define TT 12
#define CC 64
#define NN 10000
#define HH 64
#define LL 2
#define NEDGE 2000
#define NNZT 80000
#define KTOP 10
#define DEMB 16
#define BT (BB*TT)

typedef long long ll;
typedef unsigned long long u64;

__device__ __forceinline__ float4 f4z() { return make_float4(0.f,0.f,0.f,0.f); }
__device__ __forceinline__ void f4add(float4& a, const float4 b){ a.x+=b.x; a.y+=b.y; a.z+=b.z; a.w+=b.w; }
__device__ __forceinline__ void f4fma(float4& a, float w, const float4 b){ a.x+=w*b.x; a.y+=w*b.y; a.z+=w*b.z; a.w+=w*b.w; }

// ---------------- graph setup ----------------
__global__ void deg_kernel(const int* __restrict__ nidx, const int* __restrict__ eidx,
                           int* __restrict__ ndeg, int* __restrict__ edeg) {
  int i = blockIdx.x*256 + threadIdx.x;
  if (i < NNZT) { atomicAdd(&ndeg[nidx[i]],1); atomicAdd(&edeg[eidx[i]],1); }
}

__global__ void exscan_kernel(const int* __restrict__ cnt, int* __restrict__ off, int n) {
  __shared__ int part[256];
  int tid = threadIdx.x;
  int chunk = (n + 255)/256;
  int lo = tid*chunk, hi = min(lo+chunk, n);
  int s = 0;
  for (int i=lo; i<hi; ++i) s += cnt[i];
  part[tid]=s; __syncthreads();
  if (tid==0){ int acc=0; for(int i=0;i<256;++i){int v=part[i];part[i]=acc;acc+=v;} off[n]=acc; }
  __syncthreads();
  int acc = part[tid];
  for (int i=lo; i<hi; ++i){ off[i]=acc; acc+=cnt[i]; }
}

__global__ void fill_csr_kernel(const int* __restrict__ nidx, const int* __restrict__ eidx,
                                const int* __restrict__ noff, const int* __restrict__ eoff,
                                int* __restrict__ ncur, int* __restrict__ ecur,
                                int* __restrict__ node_edges, int* __restrict__ edge_nodes) {
  int i = blockIdx.x*256 + threadIdx.x;
  if (i >= NNZT) return;
  int n = nidx[i], e = eidx[i];
  int pn = atomicAdd(&ncur[n],1);
  node_edges[noff[n]+pn] = e;
  int pe = atomicAdd(&ecur[e],1);
  edge_nodes[eoff[e]+pe] = n;
}

__global__ void invdeg_kernel(const int* __restrict__ ndeg, const int* __restrict__ edeg,
                              float* __restrict__ inv_n, float* __restrict__ inv_e) {
  int i = blockIdx.x*256+threadIdx.x;
  if (i < NN) inv_n[i] = 1.0f/fmaxf((float)ndeg[i],1.0f);
  if (i < NEDGE) inv_e[i] = 1.0f/fmaxf((float)edeg[i],1.0f);
}

// ---------------- top-k: wave-uniform threshold + buffered bitonic reselect ----------------
__device__ __forceinline__ u64 sortstep(u64 X, int j, bool dir, int lane) {
  u64 p = __shfl_xor(X, j);
  bool lower = ((lane & j) == 0);
  bool keep_min = (dir == lower);
  bool xlt = (X < p);
  u64 mn = xlt ? X : p;
  u64 mx = xlt ? p : X;
  return keep_min ? mn : mx;
}

__device__ __forceinline__ void reselect(u64* bq, u64& thr, int& cnt, int lane) {
  int tot = 10 + cnt;                       // <= 113 < 128
  u64 A = (lane < tot)      ? bq[lane]      : 0ull;
  u64 B = (lane + 64 < tot) ? bq[lane + 64] : 0ull;
  for (int k = 2; k <= 32; k <<= 1) {
    for (int j = k >> 1; j >= 1; j >>= 1) {
      bool dir = ((lane & k) == 0);
      A = sortstep(A, j, dir, lane);
      B = sortstep(B, j, dir, lane);
    }
  }
  for (int j = 32; j >= 1; j >>= 1) {
    A = sortstep(A, j, true,  lane);
    B = sortstep(B, j, false, lane);
  }
  {
    bool lt = (A < B);
    u64 mn = lt ? A : B, mx = lt ? B : A;
    A = mn; B = mx;
  }
  for (int j = 32; j >= 1; j >>= 1) {
    A = sortstep(A, j, true, lane);
    B = sortstep(B, j, true, lane);
  }
  if (lane >= 54) bq[63 - lane] = B;
  thr = __shfl(B, 54);
  cnt = 0;
}

__global__ void __launch_bounds__(256) topk_kernel(const float* __restrict__ E,
                                                   int* __restrict__ tk_idx,
                                                   float* __restrict__ tk_w) {
  __shared__ u64 buf[16][128];
  int tid = threadIdx.x;
  int wv = tid >> 6, lane = tid & 63;
  int qbase = blockIdx.x*16 + wv*4;         // 625*16 = 10000 exactly
  const float4* E4 = (const float4*)E;
  float4 q[4][4];
  #pragma unroll
  for (int u=0;u<4;++u) {
    int n = qbase + u;
    #pragma unroll
    for (int j=0;j<4;++j) q[u][j] = E4[(ll)n*4 + j];
  }
  u64 thr[4] = {0,0,0,0};
  int cnt[4] = {0,0,0,0};
  buf[tid>>4][tid&15] = 0ull;               // each wave inits its own 4 rows
  for (int cb=0; cb<NN; cb+=64) {
    int cand = cb + lane;
    bool valid = (cand < NN);
    int ca = valid ? cand : 0;
    float4 a0 = E4[(ll)ca*4], a1 = E4[(ll)ca*4+1], a2 = E4[(ll)ca*4+2], a3 = E4[(ll)ca*4+3];
    u64 low = (u64)(0x00FFFFFFu - (unsigned)cand);
    u64 key[4];
    #pragma unroll
    for (int u=0;u<4;++u) {
      float dot = q[u][0].x*a0.x + q[u][0].y*a0.y + q[u][0].z*a0.z + q[u][0].w*a0.w
                + q[u][1].x*a1.x + q[u][1].y*a1.y + q[u][1].z*a1.z + q[u][1].w*a1.w
                + q[u][2].x*a2.x + q[u][2].y*a2.y + q[u][2].z*a2.z + q[u][2].w*a2.w
                + q[u][3].x*a3.x + q[u][3].y*a3.y + q[u][3].z*a3.z + q[u][3].w*a3.w;
      float s = fmaxf(dot, 0.f);
      u64 kk = ((u64)__float_as_uint(s) << 32) | low;
      key[u] = valid ? kk : 0ull;
    }
    #pragma unroll
    for (int u=0;u<4;++u) {
      u64 mask = __ballot(key[u] > thr[u]);
      if (mask) {
        if (key[u] > thr[u]) {
          int myofs = (int)__popcll(mask & ((1ull<<lane)-1ull));
          buf[wv*4+u][10 + cnt[u] + myofs] = key[u];
        }
        cnt[u] += (int)__popcll(mask);
        if (cnt[u] >= 40) reselect(&buf[wv*4+u][0], thr[u], cnt[u], lane);
      }
    }
  }
  #pragma unroll
  for (int u=0;u<4;++u) {
    u64* bq = &buf[wv*4+u][0];
    if (cnt[u] > 0) reselect(bq, thr[u], cnt[u], lane);
    u64 k10 = (lane < 10) ? bq[lane] : 0ull;
    float v = __uint_as_float((unsigned)(k10 >> 32));
    int idx = 0x00FFFFFF - (int)(k10 & 0xFFFFFFFFull);
    float v0 = __shfl(v, 0);
    float e = (lane < 10) ? expf(v - v0) : 0.f;
    float s = e;
    for (int o=1;o<16;o<<=1) s += __shfl_xor(s, o);
    if (lane < 10) {
      int n = qbase + u;
      tk_w[n*KTOP + lane] = e / s;
      tk_idx[n*KTOP + lane] = idx;
    }
  }
}

// ---------------- (B,T,C,N) -> (B*T, N, C) transpose ----------------
__global__ void transpose_kernel(const float* __restrict__ src, float* __restrict__ dst) {
  __shared__ float tile[32][33];
  int bt = blockIdx.z;
  int n0 = blockIdx.x*32, c0 = blockIdx.y*32;
  for (int i=threadIdx.y; i<32; i+=8) {
    int c = c0+i, nn = n0+threadIdx.x;
    tile[i][threadIdx.x] = (nn<NN)? src[((ll)bt*CC + c)*NN + nn] : 0.0f;
  }
  __syncthreads();
  for (int i=threadIdx.y; i<32; i+=8) {
    int nn = n0+i, c = c0+threadIdx.x;
    if (nn<NN) dst[((ll)bt*NN+nn)*64 + c] = tile[threadIdx.x][i];
  }
}

// ---------------- edge aggregation (float4, shfl idx broadcast) ----------------
__global__ void __launch_bounds__(256) edge_agg_kernel(
    const float4* __restrict__ f4, float4* __restrict__ eagg4,
    const int* __restrict__ eoff, const int* __restrict__ enodes,
    const float* __restrict__ inv_e) {
  int tid = threadIdx.x;
  int e = blockIdx.x*16 + (tid>>4);
  int lane = tid & 15;
  int s = blockIdx.y;
  if (e >= NEDGE) return;
  int j0 = eoff[e], j1 = eoff[e+1];
  const float4* fb = f4 + (ll)s*NN*16;
  float4 acc = f4z();
  int j = j0;
  for (; j+16 <= j1; j += 16) {
    int idx = enodes[j+lane];
    #pragma unroll
    for (int jj=0; jj<16; ++jj) {
      int node = __shfl(idx, (tid & 48) + jj, 64);
      f4add(acc, fb[(ll)node*16 + lane]);
    }
  }
  for (; j<j1; ++j) {
    int node = enodes[j];
    f4add(acc, fb[(ll)node*16 + lane]);
  }
  float sc = inv_e[e];
  acc.x*=sc; acc.y*=sc; acc.z*=sc; acc.w*=sc;
  eagg4[((ll)s*NEDGE+e)*16+lane] = acc;
}

// ---------------- conv applied to x for all (b,t) (float4) ----------------
__global__ void __launch_bounds__(256) conv_x_kernel(
    const float4* __restrict__ xt4, const float4* __restrict__ eagg4,
    const int* __restrict__ noff, const int* __restrict__ nedges,
    const float* __restrict__ inv_n,
    const int* __restrict__ tk_idx, const float* __restrict__ tk_w,
    float4* __restrict__ cx4) {
  __shared__ int tki_s[16][KTOP];
  __shared__ float tkw_s[16][KTOP];
  int tid = threadIdx.x; int s = blockIdx.y; int n0 = blockIdx.x*16;
  for (int i=tid; i<16*KTOP; i+=256) {
    int r=i/KTOP, k=i%KTOP;
    tki_s[r][k] = tk_idx[(n0+r)*KTOP+k];
    tkw_s[r][k] = tk_w[(n0+r)*KTOP+k];
  }
  __syncthreads();
  int row = tid>>4, lane = tid&15;
  int n = n0 + row;
  float4 stv = f4z();
  int j0 = noff[n], j1 = noff[n+1];
  const float4* eb = eagg4 + (ll)s*NEDGE*16;
  for (int j=j0;j<j1;++j) f4add(stv, eb[(ll)nedges[j]*16 + lane]);
  float sc = 0.5f*inv_n[n];
  float4 adv = f4z();
  const float4* xb = xt4 + (ll)s*NN*16;
  #pragma unroll
  for (int k=0;k<KTOP;++k) f4fma(adv, tkw_s[row][k], xb[(ll)tki_s[row][k]*16 + lane]);
  float4 r;
  r.x = sc*stv.x + 0.5f*adv.x;
  r.y = sc*stv.y + 0.5f*adv.y;
  r.z = sc*stv.z + 0.5f*adv.z;
  r.w = sc*stv.w + 0.5f*adv.w;
  cx4[((ll)s*NN+n)*16+lane] = r;
}

// ---------------- GRU step kernel 1: gates z,r ----------------
__global__ void __launch_bounds__(256) step_zr_kernel(
    const float4* __restrict__ h4, const float4* __restrict__ cx4,
    const float4* __restrict__ eagg4,
    const float* __restrict__ Wz, const float* __restrict__ bz,
    const int* __restrict__ noff, const int* __restrict__ nedges,
    const float* __restrict__ inv_n,
    const int* __restrict__ tk_idx, const float* __restrict__ tk_w,
    const float* __restrict__ hs,
    float* __restrict__ rh, float* __restrict__ zout, int t, int hzero) {
  __shared__ __attribute__((aligned(16))) float in_t[32][136];
  __shared__ int tki_s[32][KTOP];
  __shared__ float tkw_s[32][KTOP];
  int tid = threadIdx.x;
  int b = blockIdx.y; int n0 = blockIdx.x*32;
  int bt = b*TT + t;
  for (int i=tid; i<32*KTOP; i+=256) {
    int r=i/KTOP, k=i%KTOP; int n=n0+r;
    tki_s[r][k] = (n<NN)? tk_idx[n*KTOP+k] : 0;
    tkw_s[r][k] = (n<NN)? tk_w[n*KTOP+k] : 0.f;
  }
  __syncthreads();
  #pragma unroll
  for (int kk=0;kk<2;++kk) {
    int slot = tid + kk*256;
    int row = slot>>4, lane = slot&15;
    int n = n0 + row;
    float4 cxv = f4z(), chv = f4z();
    if (n < NN) {
      cxv = cx4[((ll)bt*NN + n)*16 + lane];
      if (!hzero) {
        float4 stv = f4z();
        int j0 = noff[n], j1 = noff[n+1];
        const float4* eb = eagg4 + (ll)b*NEDGE*16;
        for (int j=j0;j<j1;++j) f4add(stv, eb[(ll)nedges[j]*16 + lane]);
        float sc = 0.5f*inv_n[n];
        float4 adv = f4z();
        const float4* hb = h4 + (ll)b*NN*16;
        #pragma unroll
        for (int k=0;k<KTOP;++k) f4fma(adv, tkw_s[row][k], hb[(ll)tki_s[row][k]*16 + lane]);
        chv.x = sc*stv.x + 0.5f*adv.x;
        chv.y = sc*stv.y + 0.5f*adv.y;
        chv.z = sc*stv.z + 0.5f*adv.z;
        chv.w = sc*stv.w + 0.5f*adv.w;
      }
    }
    *(float4*)&in_t[row][lane*4] = cxv;
    *(float4*)&in_t[row][64+lane*4] = chv;
  }
  __syncthreads();
  int col = tid & 127, rg = tid >> 7;
  float acc[16];
  float bias = bz[col];
  #pragma unroll
  for (int r=0;r<16;++r) acc[r]=bias;
  for (int i4=0;i4<32;++i4) {
    float w0 = Wz[(i4*4+0)*128+col];
    float w1 = Wz[(i4*4+1)*128+col];
    float w2 = Wz[(i4*4+2)*128+col];
    float w3 = Wz[(i4*4+3)*128+col];
    #pragma unroll
    for (int r=0;r<16;++r) {
      const float4 v = *(const float4*)&in_t[rg*16+r][i4*4];
      acc[r] += v.x*w0 + v.y*w1 + v.z*w2 + v.w*w3;
    }
  }
  #pragma unroll
  for (int r=0;r<16;++r) {
    int n = n0 + rg*16 + r;
    if (n < NN) {
      float v = 1.0f/(1.0f+expf(-acc[r]));
      if (col < 64) zout[((ll)b*NN+n)*64+col] = v;
      else {
        int c = col-64;
        float hv = hzero ? 0.f : hs[((ll)b*NN+n)*64+c];
        rh[((ll)b*NN+n)*64+c] = v*hv;
      }
    }
  }
}

// ---------------- GRU step kernel 2: candidate, h update, output ----------------
__global__ void __launch_bounds__(256) step_hy_kernel(
    const float4* __restrict__ rh4, const float4* __restrict__ cx4,
    const float4* __restrict__ eagg4,
    const float* __restrict__ Wc, const float* __restrict__ bc,
    const float* __restrict__ Wo, const float* __restrict__ bo,
    const int* __restrict__ noff, const int* __restrict__ nedges,
    const float* __restrict__ inv_n,
    const int* __restrict__ tk_idx, const float* __restrict__ tk_w,
    const float* __restrict__ zbuf, float* __restrict__ h,
    float* __restrict__ out, int t, int hzero) {
  __shared__ __attribute__((aligned(16))) float in2[32][136];
  __shared__ float hn[32][65];
  __shared__ __attribute__((aligned(16))) float yt[64][36];
  __shared__ int tki_s[32][KTOP];
  __shared__ float tkw_s[32][KTOP];
  int tid = threadIdx.x;
  int b = blockIdx.y; int n0 = blockIdx.x*32;
  int bt = b*TT + t;
  for (int i=tid; i<32*KTOP; i+=256) {
    int r=i/KTOP, k=i%KTOP; int n=n0+r;
    tki_s[r][k] = (n<NN)? tk_idx[n*KTOP+k] : 0;
    tkw_s[r][k] = (n<NN)? tk_w[n*KTOP+k] : 0.f;
  }
  __syncthreads();
  #pragma unroll
  for (int kk=0;kk<2;++kk) {
    int slot = tid + kk*256;
    int row = slot>>4, lane = slot&15;
    int n = n0 + row;
    float4 cxv = f4z(), chv = f4z();
    if (n < NN) {
      cxv = cx4[((ll)bt*NN + n)*16 + lane];
      if (!hzero) {
        float4 stv = f4z();
        int j0 = noff[n], j1 = noff[n+1];
        const float4* eb = eagg4 + (ll)b*NEDGE*16;
        for (int j=j0;j<j1;++j) f4add(stv, eb[(ll)nedges[j]*16 + lane]);
        float sc = 0.5f*inv_n[n];
        float4 adv = f4z();
        const float4* rb = rh4 + (ll)b*NN*16;
        #pragma unroll
        for (int k=0;k<KTOP;++k) f4fma(adv, tkw_s[row][k], rb[(ll)tki_s[row][k]*16 + lane]);
        chv.x = sc*stv.x + 0.5f*adv.x;
        chv.y = sc*stv.y + 0.5f*adv.y;
        chv.z = sc*stv.z + 0.5f*adv.z;
        chv.w = sc*stv.w + 0.5f*adv.w;
      }
    }
    *(float4*)&in2[row][lane*4] = cxv;
    *(float4*)&in2[row][64+lane*4] = chv;
  }
  __syncthreads();
  {
    int col = tid & 63, rg = tid >> 6;
    float acc[8];
    float bias = bc[col];
    #pragma unroll
    for (int r=0;r<8;++r) acc[r]=bias;
    for (int i4=0;i4<32;++i4) {
      float w0 = Wc[(i4*4+0)*64+col];
      float w1 = Wc[(i4*4+1)*64+col];
      float w2 = Wc[(i4*4+2)*64+col];
      float w3 = Wc[(i4*4+3)*64+col];
      #pragma unroll
      for (int r=0;r<8;++r) {
        const float4 v = *(const float4*)&in2[rg*8+r][i4*4];
        acc[r] += v.x*w0+v.y*w1+v.z*w2+v.w*w3;
      }
    }
    #pragma unroll
    for (int r=0;r<8;++r) {
      int row = rg*8+r; int n = n0+row;
      float hnew = 0.0f;
      if (n<NN) {
        float cval = tanhf(acc[r]);
        float z = zbuf[((ll)b*NN+n)*64+col];
        float hv = hzero ? 0.f : h[((ll)b*NN+n)*64+col];
        hnew = z*hv + (1.0f-z)*cval;
        h[((ll)b*NN+n)*64+col] = hnew;
      }
      hn[row][col] = hnew;
    }
  }
  __syncthreads();
  {
    int col = tid & 63, rg = tid >> 6;
    float acc[8];
    float bias = bo[col];
    #pragma unroll
    for (int r=0;r<8;++r) acc[r]=bias;
    for (int i4=0;i4<16;++i4) {
      float w0 = Wo[(i4*4+0)*64+col];
      float w1 = Wo[(i4*4+1)*64+col];
      float w2 = Wo[(i4*4+2)*64+col];
      float w3 = Wo[(i4*4+3)*64+col];
      #pragma unroll
      for (int r=0;r<8;++r) {
        float vx = hn[rg*8+r][i4*4+0];
        float vy = hn[rg*8+r][i4*4+1];
        float vz = hn[rg*8+r][i4*4+2];
        float vw = hn[rg*8+r][i4*4+3];
        acc[r] += vx*w0+vy*w1+vz*w2+vw*w3;
      }
    }
    #pragma unroll
    for (int r=0;r<8;++r) yt[col][rg*8+r] = acc[r];
  }
  __syncthreads();
  #pragma unroll
  for (int kk=0;kk<2;++kk) {
    int slot = tid + kk*256;
    int col = slot>>3, q = slot&7;
    int n = n0 + q*4;
    if (n < NN) {
      float4 y = *(const float4*)&yt[col][q*4];
      float4* dst = (float4*)&out[((ll)bt*64+col)*NN + n];
      float4 cur = *dst;
      cur.x += y.x; cur.y += y.y; cur.z += y.z; cur.w += y.w;
      *dst = cur;
    }
  }
}

extern "C" void kernel_launch(void* const* d_in, const int* in_sizes, int n_in,
                              void* d_out, int out_size, void* d_ws, size_t ws_size,
                              hipStream_t stream) {
  const float* x    = (const float*)d_in[0];
  const int*  hidx  = (const int*)d_in[1];
  const float* embs = (const float*)d_in[2];
  const float* W_zr = (const float*)d_in[3];
  const float* b_zr = (const float*)d_in[4];
  const float* W_c  = (const float*)d_in[5];
  const float* b_c  = (const float*)d_in[6];
  const float* W_out= (const float*)d_in[7];
  const float* b_out= (const float*)d_in[8];
  const int* node_idx = hidx;
  const int* edge_idx = hidx + NNZT;

  char* ws = (char*)d_ws;
  size_t off = 0;
  auto alloc = [&](size_t bytes) -> void* {
    void* p = ws + off; off += (bytes + 255) & ~(size_t)255; return p;
  };
  float* xt    = (float*)alloc((size_t)BT*NN*64*4);
  float* cx    = (float*)alloc((size_t)BT*NN*64*4);
  float* eaggx = (float*)alloc((size_t)BT*NEDGE*64*4);
  float* eaggh = (float*)alloc((size_t)BB*NEDGE*64*4);
  float* hbuf  = (float*)alloc((size_t)BB*NN*64*4);
  float* rhbuf = (float*)alloc((size_t)BB*NN*64*4);
  float* zbuf  = (float*)alloc((size_t)BB*NN*64*4);
  float* tkw   = (float*)alloc((size_t)NN*KTOP*4);
  float* inv_e = (float*)alloc(NEDGE*4);
  float* inv_n = (float*)alloc(NN*4);
  int* tki     = (int*)alloc((size_t)NN*KTOP*4);
  int* ndeg    = (int*)alloc(NN*4);
  int* edeg    = (int*)alloc(NEDGE*4);
  int* noff    = (int*)alloc((NN+1)*4);
  int* eoff    = (int*)alloc((NEDGE+1)*4);
  int* ncur    = (int*)alloc(NN*4);
  int* ecur    = (int*)alloc(NEDGE*4);
  int* nedges  = (int*)alloc(NNZT*4);
  int* enodes  = (int*)alloc(NNZT*4);
  if (off > ws_size) {
    fprintf(stderr, "kernel_launch: ws too small, need %zu have %zu\n", off, ws_size);
    return;
  }

  // out starts as x (residual base)
  hipMemcpyAsync(d_out, x, (size_t)BB*TT*CC*NN*4, hipMemcpyDeviceToDevice, stream);

  // graph structure (once)
  hipMemsetAsync(ndeg, 0, NN*4, stream);
  hipMemsetAsync(edeg, 0, NEDGE*4, stream);
  hipMemsetAsync(ncur, 0, NN*4, stream);
  hipMemsetAsync(ecur, 0, NEDGE*4, stream);
  deg_kernel<<<(NNZT+255)/256,256,0,stream>>>(node_idx, edge_idx, ndeg, edeg);
  exscan_kernel<<<1,256,0,stream>>>(ndeg, noff, NN);
  exscan_kernel<<<1,256,0,stream>>>(edeg, eoff, NEDGE);
  fill_csr_kernel<<<(NNZT+255)/256,256,0,stream>>>(node_idx, edge_idx, noff, eoff,
                                                   ncur, ecur, nedges, enodes);
  invdeg_kernel<<<(NN+255)/256,256,0,stream>>>(ndeg, edeg, inv_n, inv_e);

  float* outp = (float*)d_out;
  int nblk = (NN + 31)/32;  // 313
  for (int l=0; l<LL; ++l) {
    topk_kernel<<<625,256,0,stream>>>(embs + (size_t)l*NN*DEMB, tki, tkw);
    transpose_kernel<<<dim3((NN+31)/32, CC/32, BT), dim3(32,8), 0, stream>>>(outp, xt);
    edge_agg_kernel<<<dim3(125, BT),256,0,stream>>>(
        (const float4*)xt, (float4*)eaggx, eoff, enodes, inv_e);
    conv_x_kernel<<<dim3(NN/16, BT),256,0,stream>>>(
        (const float4*)xt, (const float4*)eaggx, noff, nedges, inv_n, tki, tkw, (float4*)cx);
    const float* Wz = W_zr + (size_t)l*128*128; const float* bz = b_zr + l*128;
    const float* Wc = W_c  + (size_t)l*128*64;  const float* bc = b_c + l*64;
    const float* Wo = W_out+ (size_t)l*64*64;   const float* bo = b_out + l*64;
    for (int t=0; t<TT; ++t) {
      int hz = (t==0) ? 1 : 0;
      if (!hz)
        edge_agg_kernel<<<dim3(125, BB),256,0,stream>>>(
            (const float4*)hbuf, (float4*)eaggh, eoff, enodes, inv_e);
      step_zr_kernel<<<dim3(nblk, BB),256,0,stream>>>(
          (const float4*)hbuf, (const float4*)cx, (const float4*)eaggh, Wz, bz,
          noff, nedges, inv_n, tki, tkw, hbuf, rhbuf, zbuf, t, hz);
      if (!hz)
        edge_agg_kernel<<<dim3(125, BB),256,0,stream>>>(
            (const float4*)rhbuf, (float4*)eaggh, eoff, enodes, inv_e);
      step_hy_kernel<<<dim3(nblk, BB),256,0,stream>>>(
          (const float4*)rhbuf, (const float4*)cx, (const float4*)eaggh, Wc, bc, Wo, bo,
          noff, nedges, inv_n, tki, tkw, zbuf, hbuf, outp, t, hz);
    }
  }
}

// Round 7
// 4332.616 us; speedup vs baseline: 4.2874x; 1.1572x over previous
//
#include <hip/hip_runtime.h>
#include <hip/hip_fp16.h>
#include <cstdio>

#define BB 4
#define TT 12
#define CC 64
#define NN 10000
#define HH 64
#define LL 2
#define NEDGE 2000
#define NNZT 80000
#define KTOP 10
#define DEMB 16
#define BT (BB*TT)
#define NQR 4
#define QRS 2500

typedef long long ll;
typedef unsigned long long u64;

// ---------- fp16 row helpers: 8 channels per uint4 ----------
__device__ __forceinline__ void up8(const uint4 v, float* f) {
  const __half2* p = reinterpret_cast<const __half2*>(&v);
  float2 t0 = __half22float2(p[0]);
  float2 t1 = __half22float2(p[1]);
  float2 t2 = __half22float2(p[2]);
  float2 t3 = __half22float2(p[3]);
  f[0]=t0.x; f[1]=t0.y; f[2]=t1.x; f[3]=t1.y;
  f[4]=t2.x; f[5]=t2.y; f[6]=t3.x; f[7]=t3.y;
}
__device__ __forceinline__ uint4 pk8(const float* f) {
  __half2 h0 = __floats2half2_rn(f[0], f[1]);
  __half2 h1 = __floats2half2_rn(f[2], f[3]);
  __half2 h2 = __floats2half2_rn(f[4], f[5]);
  __half2 h3 = __floats2half2_rn(f[6], f[7]);
  uint4 r;
  r.x = *reinterpret_cast<unsigned*>(&h0);
  r.y = *reinterpret_cast<unsigned*>(&h1);
  r.z = *reinterpret_cast<unsigned*>(&h2);
  r.w = *reinterpret_cast<unsigned*>(&h3);
  return r;
}

// ---------------- graph setup ----------------
__global__ void deg_kernel(const int* __restrict__ nidx, const int* __restrict__ eidx,
                           int* __restrict__ ndeg, int* __restrict__ edeg) {
  int i = blockIdx.x*256 + threadIdx.x;
  if (i < NNZT) { atomicAdd(&ndeg[nidx[i]],1); atomicAdd(&edeg[eidx[i]],1); }
}

__global__ void exscan_kernel(const int* __restrict__ cnt, int* __restrict__ off, int n) {
  __shared__ int part[256];
  int tid = threadIdx.x;
  int chunk = (n + 255)/256;
  int lo = tid*chunk, hi = min(lo+chunk, n);
  int s = 0;
  for (int i=lo; i<hi; ++i) s += cnt[i];
  part[tid]=s; __syncthreads();
  if (tid==0){ int acc=0; for(int i=0;i<256;++i){int v=part[i];part[i]=acc;acc+=v;} off[n]=acc; }
  __syncthreads();
  int acc = part[tid];
  for (int i=lo; i<hi; ++i){ off[i]=acc; acc+=cnt[i]; }
}

__global__ void fill_csr_kernel(const int* __restrict__ nidx, const int* __restrict__ eidx,
                                const int* __restrict__ noff, const int* __restrict__ eoff,
                                int* __restrict__ ncur, int* __restrict__ ecur,
                                int* __restrict__ node_edges, int* __restrict__ edge_nodes) {
  int i = blockIdx.x*256 + threadIdx.x;
  if (i >= NNZT) return;
  int n = nidx[i], e = eidx[i];
  int pn = atomicAdd(&ncur[n],1);
  node_edges[noff[n]+pn] = e;
  int pe = atomicAdd(&ecur[e],1);
  edge_nodes[eoff[e]+pe] = n;
}

__global__ void invdeg_kernel(const int* __restrict__ ndeg, const int* __restrict__ edeg,
                              float* __restrict__ inv_n, float* __restrict__ inv_e) {
  int i = blockIdx.x*256+threadIdx.x;
  if (i < NN) inv_n[i] = 1.0f/fmaxf((float)ndeg[i],1.0f);
  if (i < NEDGE) inv_e[i] = 1.0f/fmaxf((float)edeg[i],1.0f);
}

// ---------------- top-k: wave-uniform threshold + buffered bitonic reselect ----------------
__device__ __forceinline__ u64 sortstep(u64 X, int j, bool dir, int lane) {
  u64 p = __shfl_xor(X, j);
  bool lower = ((lane & j) == 0);
  bool keep_min = (dir == lower);
  bool xlt = (X < p);
  u64 mn = xlt ? X : p;
  u64 mx = xlt ? p : X;
  return keep_min ? mn : mx;
}

__device__ __forceinline__ void reselect(u64* bq, u64& thr, int& cnt, int lane) {
  int tot = 10 + cnt;                       // <= 113 < 128
  u64 A = (lane < tot)      ? bq[lane]      : 0ull;
  u64 B = (lane + 64 < tot) ? bq[lane + 64] : 0ull;
  for (int k = 2; k <= 32; k <<= 1) {
    for (int j = k >> 1; j >= 1; j >>= 1) {
      bool dir = ((lane & k) == 0);
      A = sortstep(A, j, dir, lane);
      B = sortstep(B, j, dir, lane);
    }
  }
  for (int j = 32; j >= 1; j >>= 1) {
    A = sortstep(A, j, true,  lane);
    B = sortstep(B, j, false, lane);
  }
  {
    bool lt = (A < B);
    u64 mn = lt ? A : B, mx = lt ? B : A;
    A = mn; B = mx;
  }
  for (int j = 32; j >= 1; j >>= 1) {
    A = sortstep(A, j, true, lane);
    B = sortstep(B, j, true, lane);
  }
  if (lane >= 54) bq[63 - lane] = B;
  thr = __shfl(B, 54);
  cnt = 0;
}

// phase 1: each block covers 16 queries over candidate quarter blockIdx.y
__global__ void __launch_bounds__(256) topk_part_kernel(const float* __restrict__ E,
                                                        float* __restrict__ pv,
                                                        int* __restrict__ pi) {
  __shared__ u64 buf[16][128];
  int tid = threadIdx.x;
  int wv = tid >> 6, lane = tid & 63;
  int qbase = blockIdx.x*16 + wv*4;         // 625*16 = 10000 exactly
  int lo = blockIdx.y * QRS, hi = lo + QRS;
  const float4* E4 = (const float4*)E;
  float4 q[4][4];
  #pragma unroll
  for (int u=0;u<4;++u) {
    int n = qbase + u;
    #pragma unroll
    for (int j=0;j<4;++j) q[u][j] = E4[(ll)n*4 + j];
  }
  u64 thr[4] = {0,0,0,0};
  int cnt[4] = {0,0,0,0};
  buf[tid>>4][tid&15] = 0ull;               // waves init their own rows
  for (int cb=lo; cb<hi; cb+=64) {
    int cand = cb + lane;
    bool valid = (cand < hi);
    int ca = valid ? cand : lo;
    float4 a0 = E4[(ll)ca*4], a1 = E4[(ll)ca*4+1], a2 = E4[(ll)ca*4+2], a3 = E4[(ll)ca*4+3];
    u64 low = (u64)(0x00FFFFFFu - (unsigned)cand);
    u64 key[4];
    #pragma unroll
    for (int u=0;u<4;++u) {
      float dot = q[u][0].x*a0.x + q[u][0].y*a0.y + q[u][0].z*a0.z + q[u][0].w*a0.w
                + q[u][1].x*a1.x + q[u][1].y*a1.y + q[u][1].z*a1.z + q[u][1].w*a1.w
                + q[u][2].x*a2.x + q[u][2].y*a2.y + q[u][2].z*a2.z + q[u][2].w*a2.w
                + q[u][3].x*a3.x + q[u][3].y*a3.y + q[u][3].z*a3.z + q[u][3].w*a3.w;
      float s = fmaxf(dot, 0.f);
      u64 kk = ((u64)__float_as_uint(s) << 32) | low;
      key[u] = valid ? kk : 0ull;
    }
    #pragma unroll
    for (int u=0;u<4;++u) {
      u64 mask = __ballot(key[u] > thr[u]);
      if (mask) {
        if (key[u] > thr[u]) {
          int myofs = (int)__popcll(mask & ((1ull<<lane)-1ull));
          buf[wv*4+u][10 + cnt[u] + myofs] = key[u];
        }
        cnt[u] += (int)__popcll(mask);
        if (cnt[u] >= 40) reselect(&buf[wv*4+u][0], thr[u], cnt[u], lane);
      }
    }
  }
  #pragma unroll
  for (int u=0;u<4;++u) {
    u64* bq = &buf[wv*4+u][0];
    if (cnt[u] > 0) reselect(bq, thr[u], cnt[u], lane);
    if (lane < 10) {
      u64 k10 = bq[lane];
      float v = __uint_as_float((unsigned)(k10 >> 32));
      int idx = 0x00FFFFFF - (int)(k10 & 0xFFFFFFFFull);
      ll base = ((ll)blockIdx.y*NN + qbase + u)*KTOP + lane;
      pv[base] = v;
      pi[base] = idx;
    }
  }
}

// phase 2: merge NQR sorted partials + softmax
__global__ void topk_merge_kernel(const float* __restrict__ pv, const int* __restrict__ pi,
                                  int* __restrict__ tk_idx, float* __restrict__ tk_w) {
  int n = blockIdx.x*256 + threadIdx.x;
  if (n >= NN) return;
  float tv[KTOP]; int ti[KTOP];
  #pragma unroll
  for (int k=0;k<KTOP;++k){ tv[k]=-1.f; ti[k]=0x7fffffff; }
  for (int qr=0; qr<NQR; ++qr) {
    const float* pvp = pv + ((ll)qr*NN+n)*KTOP;
    const int*  pip = pi + ((ll)qr*NN+n)*KTOP;
    for (int k=0;k<KTOP;++k) {
      float cv = pvp[k]; int ci = pip[k];
      if (!(cv>tv[KTOP-1] || (cv==tv[KTOP-1] && ci<ti[KTOP-1]))) break;  // sorted partial
      #pragma unroll
      for (int q=0;q<KTOP;++q){
        bool better=(cv>tv[q])||(cv==tv[q]&&ci<ti[q]);
        float nv=better?cv:tv[q]; int ni=better?ci:ti[q];
        float ov=better?tv[q]:cv; int oi=better?ti[q]:ci;
        tv[q]=nv; ti[q]=ni; cv=ov; ci=oi;
      }
    }
  }
  float mx = tv[0];
  float w[KTOP]; float sum=0.f;
  #pragma unroll
  for (int k=0;k<KTOP;++k){ w[k]=expf(tv[k]-mx); sum+=w[k]; }
  float inv = 1.f/sum;
  #pragma unroll
  for (int k=0;k<KTOP;++k){ tk_w[n*KTOP+k]=w[k]*inv; tk_idx[n*KTOP+k]=ti[k]; }
}

// ---------------- (B,T,C,N) fp32 -> (B*T, N, C) fp16 transpose ----------------
__global__ void transpose_kernel(const float* __restrict__ src, __half* __restrict__ dst) {
  __shared__ float tile[32][33];
  int bt = blockIdx.z;
  int n0 = blockIdx.x*32, c0 = blockIdx.y*32;
  for (int i=threadIdx.y; i<32; i+=8) {
    int c = c0+i, nn = n0+threadIdx.x;
    tile[i][threadIdx.x] = (nn<NN)? src[((ll)bt*CC + c)*NN + nn] : 0.0f;
  }
  __syncthreads();
  for (int i=threadIdx.y; i<32; i+=8) {
    int nn = n0+i, c = c0+threadIdx.x;
    if (nn<NN) dst[((ll)bt*NN+nn)*64 + c] = __float2half_rn(tile[threadIdx.x][i]);
  }
}

// ---------------- edge aggregation (fp16 rows, 8 lanes x 2 entry-halves per edge) ----------------
__global__ void __launch_bounds__(256) edge_agg_kernel(
    const uint4* __restrict__ f8, uint4* __restrict__ eagg8,
    const int* __restrict__ eoff, const int* __restrict__ enodes,
    const float* __restrict__ inv_e) {
  int tid = threadIdx.x;
  int e = blockIdx.x*16 + (tid>>4);
  int hsel = (tid>>3)&1;
  int lane8 = tid&7;
  int s = blockIdx.y;
  float acc[8] = {0,0,0,0,0,0,0,0};
  if (e < NEDGE) {
    int j0 = eoff[e], j1 = eoff[e+1];
    const uint4* fb = f8 + (ll)s*NN*8;
    for (int j = j0 + hsel; j < j1; j += 2) {
      float t[8]; up8(fb[(ll)enodes[j]*8 + lane8], t);
      #pragma unroll
      for (int q=0;q<8;++q) acc[q] += t[q];
    }
  }
  #pragma unroll
  for (int q=0;q<8;++q) acc[q] += __shfl_xor(acc[q], 8);
  if (e < NEDGE && hsel == 0) {
    float sc = inv_e[e];
    #pragma unroll
    for (int q=0;q<8;++q) acc[q] *= sc;
    eagg8[((ll)s*NEDGE+e)*8 + lane8] = pk8(acc);
  }
}

// ---------------- conv applied to x for all (b,t) ----------------
__global__ void __launch_bounds__(256) conv_x_kernel(
    const uint4* __restrict__ xt8, const uint4* __restrict__ eagg8,
    const int* __restrict__ noff, const int* __restrict__ nedges,
    const float* __restrict__ inv_n,
    const int* __restrict__ tk_idx, const float* __restrict__ tk_w,
    uint4* __restrict__ cx8) {
  __shared__ int tki_s[32][KTOP];
  __shared__ float tkw_s[32][KTOP];
  int tid = threadIdx.x; int s = blockIdx.y; int n0 = blockIdx.x*32;
  for (int i=tid; i<32*KTOP; i+=256) {
    int r=i/KTOP, k=i%KTOP; int n = n0+r;
    tki_s[r][k] = (n<NN)? tk_idx[n*KTOP+k] : 0;
    tkw_s[r][k] = (n<NN)? tk_w[n*KTOP+k] : 0.f;
  }
  __syncthreads();
  int row = tid>>3, lane8 = tid&7;
  int n = n0 + row;
  if (n >= NN) return;
  float stv[8] = {0,0,0,0,0,0,0,0};
  const uint4* eb = eagg8 + (ll)s*NEDGE*8;
  int j0 = noff[n], j1 = noff[n+1];
  for (int j=j0;j<j1;++j) {
    float t[8]; up8(eb[(ll)nedges[j]*8 + lane8], t);
    #pragma unroll
    for (int q=0;q<8;++q) stv[q] += t[q];
  }
  float sc = 0.5f*inv_n[n];
  float adv[8] = {0,0,0,0,0,0,0,0};
  const uint4* xb = xt8 + (ll)s*NN*8;
  #pragma unroll
  for (int k=0;k<KTOP;++k) {
    float w = tkw_s[row][k];
    float t[8]; up8(xb[(ll)tki_s[row][k]*8 + lane8], t);
    #pragma unroll
    for (int q=0;q<8;++q) adv[q] += w*t[q];
  }
  float r8[8];
  #pragma unroll
  for (int q=0;q<8;++q) r8[q] = sc*stv[q] + 0.5f*adv[q];
  cx8[((ll)s*NN+n)*8+lane8] = pk8(r8);
}

// ---------------- GRU step kernel 1: gates z,r ----------------
__global__ void __launch_bounds__(256) step_zr_kernel(
    const uint4* __restrict__ h8, const uint4* __restrict__ cx8,
    const uint4* __restrict__ eagg8,
    const float* __restrict__ Wz, const float* __restrict__ bz,
    const int* __restrict__ noff, const int* __restrict__ nedges,
    const float* __restrict__ inv_n,
    const int* __restrict__ tk_idx, const float* __restrict__ tk_w,
    const __half* __restrict__ hs,
    __half* __restrict__ rh, __half* __restrict__ zout, int t, int hzero) {
  __shared__ __attribute__((aligned(16))) float in_t[32][136];
  __shared__ int tki_s[32][KTOP];
  __shared__ float tkw_s[32][KTOP];
  int tid = threadIdx.x;
  int b = blockIdx.y; int n0 = blockIdx.x*32;
  int bt = b*TT + t;
  for (int i=tid; i<32*KTOP; i+=256) {
    int r=i/KTOP, k=i%KTOP; int n=n0+r;
    tki_s[r][k] = (n<NN)? tk_idx[n*KTOP+k] : 0;
    tkw_s[r][k] = (n<NN)? tk_w[n*KTOP+k] : 0.f;
  }
  __syncthreads();
  {
    int row = tid>>3, lane8 = tid&7;
    int n = n0 + row;
    float cxv[8] = {0,0,0,0,0,0,0,0};
    float chv[8] = {0,0,0,0,0,0,0,0};
    if (n < NN) {
      up8(cx8[((ll)bt*NN + n)*8 + lane8], cxv);
      if (!hzero) {
        float stv[8] = {0,0,0,0,0,0,0,0};
        int j0 = noff[n], j1 = noff[n+1];
        const uint4* eb = eagg8 + (ll)b*NEDGE*8;
        for (int j=j0;j<j1;++j) {
          float t8[8]; up8(eb[(ll)nedges[j]*8 + lane8], t8);
          #pragma unroll
          for (int q=0;q<8;++q) stv[q] += t8[q];
        }
        float sc = 0.5f*inv_n[n];
        const uint4* hb = h8 + (ll)b*NN*8;
        float adv[8] = {0,0,0,0,0,0,0,0};
        #pragma unroll
        for (int k=0;k<KTOP;++k) {
          float w = tkw_s[row][k];
          float t8[8]; up8(hb[(ll)tki_s[row][k]*8 + lane8], t8);
          #pragma unroll
          for (int q=0;q<8;++q) adv[q] += w*t8[q];
        }
        #pragma unroll
        for (int q=0;q<8;++q) chv[q] = sc*stv[q] + 0.5f*adv[q];
      }
    }
    *(float4*)&in_t[row][lane8*8]      = make_float4(cxv[0],cxv[1],cxv[2],cxv[3]);
    *(float4*)&in_t[row][lane8*8+4]    = make_float4(cxv[4],cxv[5],cxv[6],cxv[7]);
    *(float4*)&in_t[row][64+lane8*8]   = make_float4(chv[0],chv[1],chv[2],chv[3]);
    *(float4*)&in_t[row][64+lane8*8+4] = make_float4(chv[4],chv[5],chv[6],chv[7]);
  }
  __syncthreads();
  int col = tid & 127, rg = tid >> 7;
  float acc[16];
  float bias = bz[col];
  #pragma unroll
  for (int r=0;r<16;++r) acc[r]=bias;
  for (int i4=0;i4<32;++i4) {
    float w0 = Wz[(i4*4+0)*128+col];
    float w1 = Wz[(i4*4+1)*128+col];
    float w2 = Wz[(i4*4+2)*128+col];
    float w3 = Wz[(i4*4+3)*128+col];
    #pragma unroll
    for (int r=0;r<16;++r) {
      const float4 v = *(const float4*)&in_t[rg*16+r][i4*4];
      acc[r] += v.x*w0 + v.y*w1 + v.z*w2 + v.w*w3;
    }
  }
  #pragma unroll
  for (int r=0;r<16;++r) {
    int n = n0 + rg*16 + r;
    if (n < NN) {
      float v = 1.0f/(1.0f+expf(-acc[r]));
      if (col < 64) zout[((ll)b*NN+n)*64+col] = __float2half_rn(v);
      else {
        int c = col-64;
        float hv = hzero ? 0.f : __half2float(hs[((ll)b*NN+n)*64+c]);
        rh[((ll)b*NN+n)*64+c] = __float2half_rn(v*hv);
      }
    }
  }
}

// ---------------- GRU step kernel 2: candidate, h update, output ----------------
__global__ void __launch_bounds__(256) step_hy_kernel(
    const uint4* __restrict__ rh8, const uint4* __restrict__ cx8,
    const uint4* __restrict__ eagg8,
    const float* __restrict__ Wc, const float* __restrict__ bc,
    const float* __restrict__ Wo, const float* __restrict__ bo,
    const int* __restrict__ noff, const int* __restrict__ nedges,
    const float* __restrict__ inv_n,
    const int* __restrict__ tk_idx, const float* __restrict__ tk_w,
    const __half* __restrict__ zbuf, __half* __restrict__ h,
    float* __restrict__ out, int t, int hzero) {
  __shared__ __attribute__((aligned(16))) float in2[32][136];
  __shared__ float hn[32][65];
  __shared__ __attribute__((aligned(16))) float yt[64][36];
  __shared__ int tki_s[32][KTOP];
  __shared__ float tkw_s[32][KTOP];
  int tid = threadIdx.x;
  int b = blockIdx.y; int n0 = blockIdx.x*32;
  int bt = b*TT + t;
  for (int i=tid; i<32*KTOP; i+=256) {
    int r=i/KTOP, k=i%KTOP; int n=n0+r;
    tki_s[r][k] = (n<NN)? tk_idx[n*KTOP+k] : 0;
    tkw_s[r][k] = (n<NN)? tk_w[n*KTOP+k] : 0.f;
  }
  __syncthreads();
  {
    int row = tid>>3, lane8 = tid&7;
    int n = n0 + row;
    float cxv[8] = {0,0,0,0,0,0,0,0};
    float chv[8] = {0,0,0,0,0,0,0,0};
    if (n < NN) {
      up8(cx8[((ll)bt*NN + n)*8 + lane8], cxv);
      if (!hzero) {
        float stv[8] = {0,0,0,0,0,0,0,0};
        int j0 = noff[n], j1 = noff[n+1];
        const uint4* eb = eagg8 + (ll)b*NEDGE*8;
        for (int j=j0;j<j1;++j) {
          float t8[8]; up8(eb[(ll)nedges[j]*8 + lane8], t8);
          #pragma unroll
          for (int q=0;q<8;++q) stv[q] += t8[q];
        }
        float sc = 0.5f*inv_n[n];
        const uint4* rb = rh8 + (ll)b*NN*8;
        float adv[8] = {0,0,0,0,0,0,0,0};
        #pragma unroll
        for (int k=0;k<KTOP;++k) {
          float w = tkw_s[row][k];
          float t8[8]; up8(rb[(ll)tki_s[row][k]*8 + lane8], t8);
          #pragma unroll
          for (int q=0;q<8;++q) adv[q] += w*t8[q];
        }
        #pragma unroll
        for (int q=0;q<8;++q) chv[q] = sc*stv[q] + 0.5f*adv[q];
      }
    }
    *(float4*)&in2[row][lane8*8]      = make_float4(cxv[0],cxv[1],cxv[2],cxv[3]);
    *(float4*)&in2[row][lane8*8+4]    = make_float4(cxv[4],cxv[5],cxv[6],cxv[7]);
    *(float4*)&in2[row][64+lane8*8]   = make_float4(chv[0],chv[1],chv[2],chv[3]);
    *(float4*)&in2[row][64+lane8*8+4] = make_float4(chv[4],chv[5],chv[6],chv[7]);
  }
  __syncthreads();
  {
    int col = tid & 63, rg = tid >> 6;
    float acc[8];
    float bias = bc[col];
    #pragma unroll
    for (int r=0;r<8;++r) acc[r]=bias;
    for (int i4=0;i4<32;++i4) {
      float w0 = Wc[(i4*4+0)*64+col];
      float w1 = Wc[(i4*4+1)*64+col];
      float w2 = Wc[(i4*4+2)*64+col];
      float w3 = Wc[(i4*4+3)*64+col];
      #pragma unroll
      for (int r=0;r<8;++r) {
        const float4 v = *(const float4*)&in2[rg*8+r][i4*4];
        acc[r] += v.x*w0+v.y*w1+v.z*w2+v.w*w3;
      }
    }
    #pragma unroll
    for (int r=0;r<8;++r) {
      int row = rg*8+r; int n = n0+row;
      float hnew = 0.0f;
      if (n<NN) {
        float cval = tanhf(acc[r]);
        float z = __half2float(zbuf[((ll)b*NN+n)*64+col]);
        float hv = hzero ? 0.f : __half2float(h[((ll)b*NN+n)*64+col]);
        hnew = z*hv + (1.0f-z)*cval;
        h[((ll)b*NN+n)*64+col] = __float2half_rn(hnew);
      }
      hn[row][col] = hnew;
    }
  }
  __syncthreads();
  {
    int col = tid & 63, rg = tid >> 6;
    float acc[8];
    float bias = bo[col];
    #pragma unroll
    for (int r=0;r<8;++r) acc[r]=bias;
    for (int i4=0;i4<16;++i4) {
      float w0 = Wo[(i4*4+0)*64+col];
      float w1 = Wo[(i4*4+1)*64+col];
      float w2 = Wo[(i4*4+2)*64+col];
      float w3 = Wo[(i4*4+3)*64+col];
      #pragma unroll
      for (int r=0;r<8;++r) {
        float vx = hn[rg*8+r][i4*4+0];
        float vy = hn[rg*8+r][i4*4+1];
        float vz = hn[rg*8+r][i4*4+2];
        float vw = hn[rg*8+r][i4*4+3];
        acc[r] += vx*w0+vy*w1+vz*w2+vw*w3;
      }
    }
    #pragma unroll
    for (int r=0;r<8;++r) yt[col][rg*8+r] = acc[r];
  }
  __syncthreads();
  #pragma unroll
  for (int kk=0;kk<2;++kk) {
    int slot = tid + kk*256;
    int col = slot>>3, q = slot&7;
    int n = n0 + q*4;
    if (n < NN) {
      float4 y = *(const float4*)&yt[col][q*4];
      float4* dst = (float4*)&out[((ll)bt*64+col)*NN + n];
      float4 cur = *dst;
      cur.x += y.x; cur.y += y.y; cur.z += y.z; cur.w += y.w;
      *dst = cur;
    }
  }
}

extern "C" void kernel_launch(void* const* d_in, const int* in_sizes, int n_in,
                              void* d_out, int out_size, void* d_ws, size_t ws_size,
                              hipStream_t stream) {
  const float* x    = (const float*)d_in[0];
  const int*  hidx  = (const int*)d_in[1];
  const float* embs = (const float*)d_in[2];
  const float* W_zr = (const float*)d_in[3];
  const float* b_zr = (const float*)d_in[4];
  const float* W_c  = (const float*)d_in[5];
  const float* b_c  = (const float*)d_in[6];
  const float* W_out= (const float*)d_in[7];
  const float* b_out= (const float*)d_in[8];
  const int* node_idx = hidx;
  const int* edge_idx = hidx + NNZT;

  char* ws = (char*)d_ws;
  size_t off = 0;
  auto alloc = [&](size_t bytes) -> void* {
    void* p = ws + off; off += (bytes + 255) & ~(size_t)255; return p;
  };
  __half* xt    = (__half*)alloc((size_t)BT*NN*64*2);
  __half* cx    = (__half*)alloc((size_t)BT*NN*64*2);
  __half* eaggx = (__half*)alloc((size_t)BT*NEDGE*64*2);
  __half* eaggh = (__half*)alloc((size_t)BB*NEDGE*64*2);
  __half* hbuf  = (__half*)alloc((size_t)BB*NN*64*2);
  __half* rhbuf = (__half*)alloc((size_t)BB*NN*64*2);
  __half* zbuf  = (__half*)alloc((size_t)BB*NN*64*2);
  float* pv    = (float*)alloc((size_t)NQR*NN*KTOP*4);
  int*   pi    = (int*)alloc((size_t)NQR*NN*KTOP*4);
  float* tkw   = (float*)alloc((size_t)NN*KTOP*4);
  float* inv_e = (float*)alloc(NEDGE*4);
  float* inv_n = (float*)alloc(NN*4);
  int* tki     = (int*)alloc((size_t)NN*KTOP*4);
  int* ndeg    = (int*)alloc(NN*4);
  int* edeg    = (int*)alloc(NEDGE*4);
  int* noff    = (int*)alloc((NN+1)*4);
  int* eoff    = (int*)alloc((NEDGE+1)*4);
  int* ncur    = (int*)alloc(NN*4);
  int* ecur    = (int*)alloc(NEDGE*4);
  int* nedges  = (int*)alloc(NNZT*4);
  int* enodes  = (int*)alloc(NNZT*4);
  if (off > ws_size) {
    fprintf(stderr, "kernel_launch: ws too small, need %zu have %zu\n", off, ws_size);
    return;
  }

  // out starts as x (residual base)
  hipMemcpyAsync(d_out, x, (size_t)BB*TT*CC*NN*4, hipMemcpyDeviceToDevice, stream);

  // graph structure (once)
  hipMemsetAsync(ndeg, 0, NN*4, stream);
  hipMemsetAsync(edeg, 0, NEDGE*4, stream);
  hipMemsetAsync(ncur, 0, NN*4, stream);
  hipMemsetAsync(ecur, 0, NEDGE*4, stream);
  deg_kernel<<<(NNZT+255)/256,256,0,stream>>>(node_idx, edge_idx, ndeg, edeg);
  exscan_kernel<<<1,256,0,stream>>>(ndeg, noff, NN);
  exscan_kernel<<<1,256,0,stream>>>(edeg, eoff, NEDGE);
  fill_csr_kernel<<<(NNZT+255)/256,256,0,stream>>>(node_idx, edge_idx, noff, eoff,
                                                   ncur, ecur, nedges, enodes);
  invdeg_kernel<<<(NN+255)/256,256,0,stream>>>(ndeg, edeg, inv_n, inv_e);

  float* outp = (float*)d_out;
  for (int l=0; l<LL; ++l) {
    topk_part_kernel<<<dim3(625, NQR),256,0,stream>>>(embs + (size_t)l*NN*DEMB, pv, pi);
    topk_merge_kernel<<<(NN+255)/256,256,0,stream>>>(pv, pi, tki, tkw);
    transpose_kernel<<<dim3((NN+31)/32, CC/32, BT), dim3(32,8), 0, stream>>>(outp, xt);
    edge_agg_kernel<<<dim3(125, BT),256,0,stream>>>(
        (const uint4*)xt, (uint4*)eaggx, eoff, enodes, inv_e);
    conv_x_kernel<<<dim3(313, BT),256,0,stream>>>(
        (const uint4*)xt, (const uint4*)eaggx, noff, nedges, inv_n, tki, tkw, (uint4*)cx);
    const float* Wz = W_zr + (size_t)l*128*128; const float* bz = b_zr + l*128;
    const float* Wc = W_c  + (size_t)l*128*64;  const float* bc = b_c + l*64;
    const float* Wo = W_out+ (size_t)l*64*64;   const float* bo = b_out + l*64;
    for (int t=0; t<TT; ++t) {
      int hz = (t==0) ? 1 : 0;
      if (!hz)
        edge_agg_kernel<<<dim3(125, BB),256,0,stream>>>(
            (const uint4*)hbuf, (uint4*)eaggh, eoff, enodes, inv_e);
      step_zr_kernel<<<dim3(313, BB),256,0,stream>>>(
          (const uint4*)hbuf, (const uint4*)cx, (const uint4*)eaggh, Wz, bz,
          noff, nedges, inv_n, tki, tkw, hbuf, rhbuf, zbuf, t, hz);
      if (!hz)
        edge_agg_kernel<<<dim3(125, BB),256,0,stream>>>(
            (const uint4*)rhbuf, (uint4*)eaggh, eoff, enodes, inv_e);
      step_hy_kernel<<<dim3(313, BB),256,0,stream>>>(
          (const uint4*)rhbuf, (const uint4*)cx, (const uint4*)eaggh, Wc, bc, Wo, bo,
          noff, nedges, inv_n, tki, tkw, zbuf, hbuf, outp, t, hz);
    }
  }
}

// Round 8
// 2867.814 us; speedup vs baseline: 6.4773x; 1.5108x over previous
//
#include <hip/hip_runtime.h>
#include <hip/hip_fp16.h>
#include <cstdio>

#define BB 4
#define TT 12
#define CC 64
#define NN 10000
#define HH 64
#define LL 2
#define NEDGE 2000
#define NNZT 80000
#define KTOP 10
#define DEMB 16
#define BT (BB*TT)

typedef long long ll;
typedef unsigned long long u64;
typedef unsigned int u32;
typedef unsigned short ushort;

typedef short bf16x8 __attribute__((ext_vector_type(8)));
typedef float f32x4 __attribute__((ext_vector_type(4)));

// ---------- fp16 row helpers: 8 channels per uint4 ----------
__device__ __forceinline__ void up8(const uint4 v, float* f) {
  const __half2* p = reinterpret_cast<const __half2*>(&v);
  float2 t0 = __half22float2(p[0]);
  float2 t1 = __half22float2(p[1]);
  float2 t2 = __half22float2(p[2]);
  float2 t3 = __half22float2(p[3]);
  f[0]=t0.x; f[1]=t0.y; f[2]=t1.x; f[3]=t1.y;
  f[4]=t2.x; f[5]=t2.y; f[6]=t3.x; f[7]=t3.y;
}
__device__ __forceinline__ uint4 pk8(const float* f) {
  __half2 h0 = __floats2half2_rn(f[0], f[1]);
  __half2 h1 = __floats2half2_rn(f[2], f[3]);
  __half2 h2 = __floats2half2_rn(f[4], f[5]);
  __half2 h3 = __floats2half2_rn(f[6], f[7]);
  uint4 r;
  r.x = *reinterpret_cast<unsigned*>(&h0);
  r.y = *reinterpret_cast<unsigned*>(&h1);
  r.z = *reinterpret_cast<unsigned*>(&h2);
  r.w = *reinterpret_cast<unsigned*>(&h3);
  return r;
}
__device__ __forceinline__ ushort f2bf(float x) {
  u32 u = __float_as_uint(x);
  u32 r = u + 0x7FFFu + ((u >> 16) & 1u);
  return (ushort)(r >> 16);
}
__device__ __forceinline__ uint4 pk8bf(const float* f) {
  uint4 r;
  r.x = (u32)f2bf(f[0]) | ((u32)f2bf(f[1])<<16);
  r.y = (u32)f2bf(f[2]) | ((u32)f2bf(f[3])<<16);
  r.z = (u32)f2bf(f[4]) | ((u32)f2bf(f[5])<<16);
  r.w = (u32)f2bf(f[6]) | ((u32)f2bf(f[7])<<16);
  return r;
}

// ---------------- graph setup ----------------
__global__ void deg_kernel(const int* __restrict__ nidx, const int* __restrict__ eidx,
                           int* __restrict__ ndeg, int* __restrict__ edeg) {
  int i = blockIdx.x*256 + threadIdx.x;
  if (i < NNZT) { atomicAdd(&ndeg[nidx[i]],1); atomicAdd(&edeg[eidx[i]],1); }
}

__global__ void exscan_kernel(const int* __restrict__ cnt, int* __restrict__ off, int n) {
  __shared__ int part[256];
  int tid = threadIdx.x;
  int chunk = (n + 255)/256;
  int lo = tid*chunk, hi = min(lo+chunk, n);
  int s = 0;
  for (int i=lo; i<hi; ++i) s += cnt[i];
  part[tid]=s; __syncthreads();
  if (tid==0){ int acc=0; for(int i=0;i<256;++i){int v=part[i];part[i]=acc;acc+=v;} off[n]=acc; }
  __syncthreads();
  int acc = part[tid];
  for (int i=lo; i<hi; ++i){ off[i]=acc; acc+=cnt[i]; }
}

__global__ void fill_csr_kernel(const int* __restrict__ nidx, const int* __restrict__ eidx,
                                const int* __restrict__ noff, const int* __restrict__ eoff,
                                int* __restrict__ ncur, int* __restrict__ ecur,
                                int* __restrict__ node_edges, int* __restrict__ edge_nodes) {
  int i = blockIdx.x*256 + threadIdx.x;
  if (i >= NNZT) return;
  int n = nidx[i], e = eidx[i];
  int pn = atomicAdd(&ncur[n],1);
  node_edges[noff[n]+pn] = e;
  int pe = atomicAdd(&ecur[e],1);
  edge_nodes[eoff[e]+pe] = n;
}

__global__ void invdeg_kernel(const int* __restrict__ ndeg, const int* __restrict__ edeg,
                              float* __restrict__ inv_n, float* __restrict__ inv_e) {
  int i = blockIdx.x*256+threadIdx.x;
  if (i < NN) inv_n[i] = 1.0f/fmaxf((float)ndeg[i],1.0f);
  if (i < NEDGE) inv_e[i] = 1.0f/fmaxf((float)edeg[i],1.0f);
}

// ---------------- weight swizzle for MFMA B operands (bf16) ----------------
// layout: [tileC][kchunk][lane][i] with element = W[k][col], k=kk*32+(lane>>4)*8+i, col=tc*16+(lane&15)
__global__ void prep_w_kernel(const float* __restrict__ Wz, const float* __restrict__ Wc,
                              const float* __restrict__ Wo,
                              short* __restrict__ Wz_sw, short* __restrict__ Wc_sw,
                              short* __restrict__ Wo_sw) {
  int idx = blockIdx.x*256 + threadIdx.x;
  if (idx < 16384) {  // Wz: [8][4][64][8], K=128, N=128
    int i = idx&7, lane = (idx>>3)&63, kk = (idx>>9)&3, tc = idx>>11;
    int k = kk*32 + (lane>>4)*8 + i, col = tc*16 + (lane&15);
    Wz_sw[idx] = (short)f2bf(Wz[k*128+col]);
  }
  if (idx < 8192) {   // Wc: [4][4][64][8], K=128, N=64
    int i = idx&7, lane = (idx>>3)&63, kk = (idx>>9)&3, tc = idx>>11;
    int k = kk*32 + (lane>>4)*8 + i, col = tc*16 + (lane&15);
    Wc_sw[idx] = (short)f2bf(Wc[k*64+col]);
  }
  if (idx < 4096) {   // Wo: [4][2][64][8], K=64, N=64
    int i = idx&7, lane = (idx>>3)&63, kk = (idx>>9)&1, tc = idx>>10;
    int k = kk*32 + (lane>>4)*8 + i, col = tc*16 + (lane&15);
    Wo_sw[idx] = (short)f2bf(Wo[k*64+col]);
  }
}

// ---------------- top-k (round-6 version: coalesced global reads, 0 conflicts) ----------------
__device__ __forceinline__ u64 sortstep(u64 X, int j, bool dir, int lane) {
  u64 p = __shfl_xor(X, j);
  bool lower = ((lane & j) == 0);
  bool keep_min = (dir == lower);
  bool xlt = (X < p);
  u64 mn = xlt ? X : p;
  u64 mx = xlt ? p : X;
  return keep_min ? mn : mx;
}

__device__ __forceinline__ void reselect(u64* bq, u64& thr, int& cnt, int lane) {
  int tot = 10 + cnt;                       // <= 113 < 128
  u64 A = (lane < tot)      ? bq[lane]      : 0ull;
  u64 B = (lane + 64 < tot) ? bq[lane + 64] : 0ull;
  for (int k = 2; k <= 32; k <<= 1) {
    for (int j = k >> 1; j >= 1; j >>= 1) {
      bool dir = ((lane & k) == 0);
      A = sortstep(A, j, dir, lane);
      B = sortstep(B, j, dir, lane);
    }
  }
  for (int j = 32; j >= 1; j >>= 1) {
    A = sortstep(A, j, true,  lane);
    B = sortstep(B, j, false, lane);
  }
  {
    bool lt = (A < B);
    u64 mn = lt ? A : B, mx = lt ? B : A;
    A = mn; B = mx;
  }
  for (int j = 32; j >= 1; j >>= 1) {
    A = sortstep(A, j, true, lane);
    B = sortstep(B, j, true, lane);
  }
  if (lane >= 54) bq[63 - lane] = B;
  thr = __shfl(B, 54);
  cnt = 0;
}

__global__ void __launch_bounds__(256) topk_kernel(const float* __restrict__ E,
                                                   int* __restrict__ tk_idx,
                                                   float* __restrict__ tk_w) {
  __shared__ u64 buf[16][128];
  int tid = threadIdx.x;
  int wv = tid >> 6, lane = tid & 63;
  int qbase = blockIdx.x*16 + wv*4;         // 625*16 = 10000 exactly
  const float4* E4 = (const float4*)E;
  float4 q[4][4];
  #pragma unroll
  for (int u=0;u<4;++u) {
    int n = qbase + u;
    #pragma unroll
    for (int j=0;j<4;++j) q[u][j] = E4[(ll)n*4 + j];
  }
  u64 thr[4] = {0,0,0,0};
  int cnt[4] = {0,0,0,0};
  buf[tid>>4][tid&15] = 0ull;
  for (int cb=0; cb<NN; cb+=64) {
    int cand = cb + lane;
    bool valid = (cand < NN);
    int ca = valid ? cand : 0;
    float4 a0 = E4[(ll)ca*4], a1 = E4[(ll)ca*4+1], a2 = E4[(ll)ca*4+2], a3 = E4[(ll)ca*4+3];
    u64 low = (u64)(0x00FFFFFFu - (unsigned)cand);
    u64 key[4];
    #pragma unroll
    for (int u=0;u<4;++u) {
      float dot = q[u][0].x*a0.x + q[u][0].y*a0.y + q[u][0].z*a0.z + q[u][0].w*a0.w
                + q[u][1].x*a1.x + q[u][1].y*a1.y + q[u][1].z*a1.z + q[u][1].w*a1.w
                + q[u][2].x*a2.x + q[u][2].y*a2.y + q[u][2].z*a2.z + q[u][2].w*a2.w
                + q[u][3].x*a3.x + q[u][3].y*a3.y + q[u][3].z*a3.z + q[u][3].w*a3.w;
      float s = fmaxf(dot, 0.f);
      u64 kk = ((u64)__float_as_uint(s) << 32) | low;
      key[u] = valid ? kk : 0ull;
    }
    #pragma unroll
    for (int u=0;u<4;++u) {
      u64 mask = __ballot(key[u] > thr[u]);
      if (mask) {
        if (key[u] > thr[u]) {
          int myofs = (int)__popcll(mask & ((1ull<<lane)-1ull));
          buf[wv*4+u][10 + cnt[u] + myofs] = key[u];
        }
        cnt[u] += (int)__popcll(mask);
        if (cnt[u] >= 40) reselect(&buf[wv*4+u][0], thr[u], cnt[u], lane);
      }
    }
  }
  #pragma unroll
  for (int u=0;u<4;++u) {
    u64* bq = &buf[wv*4+u][0];
    if (cnt[u] > 0) reselect(bq, thr[u], cnt[u], lane);
    u64 k10 = (lane < 10) ? bq[lane] : 0ull;
    float v = __uint_as_float((unsigned)(k10 >> 32));
    int idx = 0x00FFFFFF - (int)(k10 & 0xFFFFFFFFull);
    float v0 = __shfl(v, 0);
    float e = (lane < 10) ? expf(v - v0) : 0.f;
    float s = e;
    for (int o=1;o<16;o<<=1) s += __shfl_xor(s, o);
    if (lane < 10) {
      int n = qbase + u;
      tk_w[n*KTOP + lane] = e / s;
      tk_idx[n*KTOP + lane] = idx;
    }
  }
}

// ---------------- (B,T,C,N) fp32 -> (B*T, N, C) fp16 transpose ----------------
__global__ void transpose_kernel(const float* __restrict__ src, __half* __restrict__ dst) {
  __shared__ float tile[32][33];
  int bt = blockIdx.z;
  int n0 = blockIdx.x*32, c0 = blockIdx.y*32;
  for (int i=threadIdx.y; i<32; i+=8) {
    int c = c0+i, nn = n0+threadIdx.x;
    tile[i][threadIdx.x] = (nn<NN)? src[((ll)bt*CC + c)*NN + nn] : 0.0f;
  }
  __syncthreads();
  for (int i=threadIdx.y; i<32; i+=8) {
    int nn = n0+i, c = c0+threadIdx.x;
    if (nn<NN) dst[((ll)bt*NN+nn)*64 + c] = __float2half_rn(tile[threadIdx.x][i]);
  }
}

// ---------------- edge aggregation (fp16 rows) ----------------
__global__ void __launch_bounds__(256) edge_agg_kernel(
    const uint4* __restrict__ f8, uint4* __restrict__ eagg8,
    const int* __restrict__ eoff, const int* __restrict__ enodes,
    const float* __restrict__ inv_e) {
  int tid = threadIdx.x;
  int e = blockIdx.x*16 + (tid>>4);
  int hsel = (tid>>3)&1;
  int lane8 = tid&7;
  int s = blockIdx.y;
  float acc[8] = {0,0,0,0,0,0,0,0};
  if (e < NEDGE) {
    int j0 = eoff[e], j1 = eoff[e+1];
    const uint4* fb = f8 + (ll)s*NN*8;
    for (int j = j0 + hsel; j < j1; j += 2) {
      float t[8]; up8(fb[(ll)enodes[j]*8 + lane8], t);
      #pragma unroll
      for (int q=0;q<8;++q) acc[q] += t[q];
    }
  }
  #pragma unroll
  for (int q=0;q<8;++q) acc[q] += __shfl_xor(acc[q], 8);
  if (e < NEDGE && hsel == 0) {
    float sc = inv_e[e];
    #pragma unroll
    for (int q=0;q<8;++q) acc[q] *= sc;
    eagg8[((ll)s*NEDGE+e)*8 + lane8] = pk8(acc);
  }
}

// ---------------- conv applied to x for all (b,t) ----------------
__global__ void __launch_bounds__(256) conv_x_kernel(
    const uint4* __restrict__ xt8, const uint4* __restrict__ eagg8,
    const int* __restrict__ noff, const int* __restrict__ nedges,
    const float* __restrict__ inv_n,
    const int* __restrict__ tk_idx, const float* __restrict__ tk_w,
    uint4* __restrict__ cx8) {
  __shared__ int tki_s[32][KTOP];
  __shared__ float tkw_s[32][KTOP];
  int tid = threadIdx.x; int s = blockIdx.y; int n0 = blockIdx.x*32;
  for (int i=tid; i<32*KTOP; i+=256) {
    int r=i/KTOP, k=i%KTOP; int n = n0+r;
    tki_s[r][k] = (n<NN)? tk_idx[n*KTOP+k] : 0;
    tkw_s[r][k] = (n<NN)? tk_w[n*KTOP+k] : 0.f;
  }
  __syncthreads();
  int row = tid>>3, lane8 = tid&7;
  int n = n0 + row;
  if (n >= NN) return;
  float stv[8] = {0,0,0,0,0,0,0,0};
  const uint4* eb = eagg8 + (ll)s*NEDGE*8;
  int j0 = noff[n], j1 = noff[n+1];
  for (int j=j0;j<j1;++j) {
    float t[8]; up8(eb[(ll)nedges[j]*8 + lane8], t);
    #pragma unroll
    for (int q=0;q<8;++q) stv[q] += t[q];
  }
  float sc = 0.5f*inv_n[n];
  float adv[8] = {0,0,0,0,0,0,0,0};
  const uint4* xb = xt8 + (ll)s*NN*8;
  #pragma unroll
  for (int k=0;k<KTOP;++k) {
    float w = tkw_s[row][k];
    float t[8]; up8(xb[(ll)tki_s[row][k]*8 + lane8], t);
    #pragma unroll
    for (int q=0;q<8;++q) adv[q] += w*t[q];
  }
  float r8[8];
  #pragma unroll
  for (int q=0;q<8;++q) r8[q] = sc*stv[q] + 0.5f*adv[q];
  cx8[((ll)s*NN+n)*8+lane8] = pk8(r8);
}

// ---------------- GRU step kernel 1: gates z,r (MFMA GEMM) ----------------
__global__ void __launch_bounds__(256) step_zr_kernel(
    const uint4* __restrict__ h8, const uint4* __restrict__ cx8,
    const uint4* __restrict__ eagg8,
    const short* __restrict__ Wz_sw, const float* __restrict__ bz,
    const int* __restrict__ noff, const int* __restrict__ nedges,
    const float* __restrict__ inv_n,
    const int* __restrict__ tk_idx, const float* __restrict__ tk_w,
    const __half* __restrict__ hs,
    __half* __restrict__ rh, __half* __restrict__ zout, int t, int hzero) {
  __shared__ __align__(16) short in_bf[32][136];
  __shared__ int tki_s[32][KTOP];
  __shared__ float tkw_s[32][KTOP];
  int tid = threadIdx.x;
  int b = blockIdx.y; int n0 = blockIdx.x*32;
  int bt = b*TT + t;
  for (int i=tid; i<32*KTOP; i+=256) {
    int r=i/KTOP, k=i%KTOP; int n=n0+r;
    tki_s[r][k] = (n<NN)? tk_idx[n*KTOP+k] : 0;
    tkw_s[r][k] = (n<NN)? tk_w[n*KTOP+k] : 0.f;
  }
  __syncthreads();
  {
    int row = tid>>3, lane8 = tid&7;
    int n = n0 + row;
    float cxv[8] = {0,0,0,0,0,0,0,0};
    float chv[8] = {0,0,0,0,0,0,0,0};
    if (n < NN) {
      up8(cx8[((ll)bt*NN + n)*8 + lane8], cxv);
      if (!hzero) {
        float stv[8] = {0,0,0,0,0,0,0,0};
        int j0 = noff[n], j1 = noff[n+1];
        const uint4* eb = eagg8 + (ll)b*NEDGE*8;
        for (int j=j0;j<j1;++j) {
          float t8[8]; up8(eb[(ll)nedges[j]*8 + lane8], t8);
          #pragma unroll
          for (int q=0;q<8;++q) stv[q] += t8[q];
        }
        float sc = 0.5f*inv_n[n];
        const uint4* hb = h8 + (ll)b*NN*8;
        float adv[8] = {0,0,0,0,0,0,0,0};
        #pragma unroll
        for (int k=0;k<KTOP;++k) {
          float w = tkw_s[row][k];
          float t8[8]; up8(hb[(ll)tki_s[row][k]*8 + lane8], t8);
          #pragma unroll
          for (int q=0;q<8;++q) adv[q] += w*t8[q];
        }
        #pragma unroll
        for (int q=0;q<8;++q) chv[q] = sc*stv[q] + 0.5f*adv[q];
      }
    }
    *(uint4*)&in_bf[row][lane8*8]    = pk8bf(cxv);
    *(uint4*)&in_bf[row][64+lane8*8] = pk8bf(chv);
  }
  __syncthreads();
  // MFMA GEMM: C[32][128] = in_bf[32][128] x Wz[128][128]; 16 tiles of 16x16
  int wv = tid>>6, lane = tid&63;
  int m = lane&15, g = lane>>4;
  #pragma unroll
  for (int q=0;q<4;++q) {
    int T = wv*4 + q;
    int tr = T>>3, tc = T&7;
    f32x4 acc = {0.f,0.f,0.f,0.f};
    #pragma unroll
    for (int kk=0;kk<4;++kk) {
      bf16x8 a = *(const bf16x8*)&in_bf[tr*16 + m][kk*32 + g*8];
      bf16x8 bf = *(const bf16x8*)&Wz_sw[((tc*4+kk)*64 + lane)*8];
      acc = __builtin_amdgcn_mfma_f32_16x16x32_bf16(a, bf, acc, 0, 0, 0);
    }
    int col = tc*16 + m;
    float bias = bz[col];
    #pragma unroll
    for (int r=0;r<4;++r) {
      int row = tr*16 + g*4 + r;
      int n = n0 + row;
      if (n < NN) {
        float v = 1.0f/(1.0f+expf(-(acc[r]+bias)));
        if (col < 64) zout[((ll)b*NN+n)*64+col] = __float2half_rn(v);
        else {
          int c = col-64;
          float hv = hzero ? 0.f : __half2float(hs[((ll)b*NN+n)*64+c]);
          rh[((ll)b*NN+n)*64+c] = __float2half_rn(v*hv);
        }
      }
    }
  }
}

// ---------------- GRU step kernel 2: candidate, h update, output (MFMA) ----------------
__global__ void __launch_bounds__(256) step_hy_kernel(
    const uint4* __restrict__ rh8, const uint4* __restrict__ cx8,
    const uint4* __restrict__ eagg8,
    const short* __restrict__ Wc_sw, const float* __restrict__ bc,
    const short* __restrict__ Wo_sw, const float* __restrict__ bo,
    const int* __restrict__ noff, const int* __restrict__ nedges,
    const float* __restrict__ inv_n,
    const int* __restrict__ tk_idx, const float* __restrict__ tk_w,
    const __half* __restrict__ zbuf, __half* __restrict__ h,
    float* __restrict__ out, int t, int hzero) {
  __shared__ __align__(16) short in_bf[32][136];
  __shared__ __align__(16) short hn[32][72];
  __shared__ __align__(16) float yt[64][36];
  __shared__ int tki_s[32][KTOP];
  __shared__ float tkw_s[32][KTOP];
  int tid = threadIdx.x;
  int b = blockIdx.y; int n0 = blockIdx.x*32;
  int bt = b*TT + t;
  for (int i=tid; i<32*KTOP; i+=256) {
    int r=i/KTOP, k=i%KTOP; int n=n0+r;
    tki_s[r][k] = (n<NN)? tk_idx[n*KTOP+k] : 0;
    tkw_s[r][k] = (n<NN)? tk_w[n*KTOP+k] : 0.f;
  }
  __syncthreads();
  {
    int row = tid>>3, lane8 = tid&7;
    int n = n0 + row;
    float cxv[8] = {0,0,0,0,0,0,0,0};
    float chv[8] = {0,0,0,0,0,0,0,0};
    if (n < NN) {
      up8(cx8[((ll)bt*NN + n)*8 + lane8], cxv);
      if (!hzero) {
        float stv[8] = {0,0,0,0,0,0,0,0};
        int j0 = noff[n], j1 = noff[n+1];
        const uint4* eb = eagg8 + (ll)b*NEDGE*8;
        for (int j=j0;j<j1;++j) {
          float t8[8]; up8(eb[(ll)nedges[j]*8 + lane8], t8);
          #pragma unroll
          for (int q=0;q<8;++q) stv[q] += t8[q];
        }
        float sc = 0.5f*inv_n[n];
        const uint4* rb = rh8 + (ll)b*NN*8;
        float adv[8] = {0,0,0,0,0,0,0,0};
        #pragma unroll
        for (int k=0;k<KTOP;++k) {
          float w = tkw_s[row][k];
          float t8[8]; up8(rb[(ll)tki_s[row][k]*8 + lane8], t8);
          #pragma unroll
          for (int q=0;q<8;++q) adv[q] += w*t8[q];
        }
        #pragma unroll
        for (int q=0;q<8;++q) chv[q] = sc*stv[q] + 0.5f*adv[q];
      }
    }
    *(uint4*)&in_bf[row][lane8*8]    = pk8bf(cxv);
    *(uint4*)&in_bf[row][64+lane8*8] = pk8bf(chv);
  }
  __syncthreads();
  int wv = tid>>6, lane = tid&63;
  int m = lane&15, g = lane>>4;
  // GEMM1: C[32][64] = in_bf[32][128] x Wc[128][64]; 8 tiles
  #pragma unroll
  for (int q=0;q<2;++q) {
    int T = wv + 4*q;
    int tr = T>>2, tc = T&3;
    f32x4 acc = {0.f,0.f,0.f,0.f};
    #pragma unroll
    for (int kk=0;kk<4;++kk) {
      bf16x8 a = *(const bf16x8*)&in_bf[tr*16 + m][kk*32 + g*8];
      bf16x8 bf = *(const bf16x8*)&Wc_sw[((tc*4+kk)*64 + lane)*8];
      acc = __builtin_amdgcn_mfma_f32_16x16x32_bf16(a, bf, acc, 0, 0, 0);
    }
    int col = tc*16 + m;
    float bias = bc[col];
    #pragma unroll
    for (int r=0;r<4;++r) {
      int row = tr*16 + g*4 + r;
      int n = n0 + row;
      float hnew = 0.0f;
      if (n < NN) {
        float cval = tanhf(acc[r]+bias);
        float z = __half2float(zbuf[((ll)b*NN+n)*64+col]);
        float hv = hzero ? 0.f : __half2float(h[((ll)b*NN+n)*64+col]);
        hnew = z*hv + (1.0f-z)*cval;
        h[((ll)b*NN+n)*64+col] = __float2half_rn(hnew);
      }
      hn[row][col] = (short)f2bf(hnew);
    }
  }
  __syncthreads();
  // GEMM2: y[32][64] = hn[32][64] x Wo[64][64]; 8 tiles
  #pragma unroll
  for (int q=0;q<2;++q) {
    int T = wv + 4*q;
    int tr = T>>2, tc = T&3;
    f32x4 acc = {0.f,0.f,0.f,0.f};
    #pragma unroll
    for (int kk=0;kk<2;++kk) {
      bf16x8 a = *(const bf16x8*)&hn[tr*16 + m][kk*32 + g*8];
      bf16x8 bf = *(const bf16x8*)&Wo_sw[((tc*2+kk)*64 + lane)*8];
      acc = __builtin_amdgcn_mfma_f32_16x16x32_bf16(a, bf, acc, 0, 0, 0);
    }
    int col = tc*16 + m;
    float bias = bo[col];
    #pragma unroll
    for (int r=0;r<4;++r) {
      int row = tr*16 + g*4 + r;
      yt[col][row] = acc[r] + bias;
    }
  }
  __syncthreads();
  #pragma unroll
  for (int kk=0;kk<2;++kk) {
    int slot = tid + kk*256;
    int col = slot>>3, q = slot&7;
    int n = n0 + q*4;
    if (n < NN) {
      float4 y = *(const float4*)&yt[col][q*4];
      float4* dst = (float4*)&out[((ll)bt*64+col)*NN + n];
      float4 cur = *dst;
      cur.x += y.x; cur.y += y.y; cur.z += y.z; cur.w += y.w;
      *dst = cur;
    }
  }
}

extern "C" void kernel_launch(void* const* d_in, const int* in_sizes, int n_in,
                              void* d_out, int out_size, void* d_ws, size_t ws_size,
                              hipStream_t stream) {
  const float* x    = (const float*)d_in[0];
  const int*  hidx  = (const int*)d_in[1];
  const float* embs = (const float*)d_in[2];
  const float* W_zr = (const float*)d_in[3];
  const float* b_zr = (const float*)d_in[4];
  const float* W_c  = (const float*)d_in[5];
  const float* b_c  = (const float*)d_in[6];
  const float* W_out= (const float*)d_in[7];
  const float* b_out= (const float*)d_in[8];
  const int* node_idx = hidx;
  const int* edge_idx = hidx + NNZT;

  char* ws = (char*)d_ws;
  size_t off = 0;
  auto alloc = [&](size_t bytes) -> void* {
    void* p = ws + off; off += (bytes + 255) & ~(size_t)255; return p;
  };
  __half* xt    = (__half*)alloc((size_t)BT*NN*64*2);
  __half* cx    = (__half*)alloc((size_t)BT*NN*64*2);
  __half* eaggx = (__half*)alloc((size_t)BT*NEDGE*64*2);
  __half* eaggh = (__half*)alloc((size_t)BB*NEDGE*64*2);
  __half* hbuf  = (__half*)alloc((size_t)BB*NN*64*2);
  __half* rhbuf = (__half*)alloc((size_t)BB*NN*64*2);
  __half* zbuf  = (__half*)alloc((size_t)BB*NN*64*2);
  short* Wz_sw = (short*)alloc(16384*2);
  short* Wc_sw = (short*)alloc(8192*2);
  short* Wo_sw = (short*)alloc(4096*2);
  float* tkw   = (float*)alloc((size_t)NN*KTOP*4);
  float* inv_e = (float*)alloc(NEDGE*4);
  float* inv_n = (float*)alloc(NN*4);
  int* tki     = (int*)alloc((size_t)NN*KTOP*4);
  int* ndeg    = (int*)alloc(NN*4);
  int* edeg    = (int*)alloc(NEDGE*4);
  int* noff    = (int*)alloc((NN+1)*4);
  int* eoff    = (int*)alloc((NEDGE+1)*4);
  int* ncur    = (int*)alloc(NN*4);
  int* ecur    = (int*)alloc(NEDGE*4);
  int* nedges  = (int*)alloc(NNZT*4);
  int* enodes  = (int*)alloc(NNZT*4);
  if (off > ws_size) {
    fprintf(stderr, "kernel_launch: ws too small, need %zu have %zu\n", off, ws_size);
    return;
  }

  // out starts as x (residual base)
  hipMemcpyAsync(d_out, x, (size_t)BB*TT*CC*NN*4, hipMemcpyDeviceToDevice, stream);

  // graph structure (once)
  hipMemsetAsync(ndeg, 0, NN*4, stream);
  hipMemsetAsync(edeg, 0, NEDGE*4, stream);
  hipMemsetAsync(ncur, 0, NN*4, stream);
  hipMemsetAsync(ecur, 0, NEDGE*4, stream);
  deg_kernel<<<(NNZT+255)/256,256,0,stream>>>(node_idx, edge_idx, ndeg, edeg);
  exscan_kernel<<<1,256,0,stream>>>(ndeg, noff, NN);
  exscan_kernel<<<1,256,0,stream>>>(edeg, eoff, NEDGE);
  fill_csr_kernel<<<(NNZT+255)/256,256,0,stream>>>(node_idx, edge_idx, noff, eoff,
                                                   ncur, ecur, nedges, enodes);
  invdeg_kernel<<<(NN+255)/256,256,0,stream>>>(ndeg, edeg, inv_n, inv_e);

  float* outp = (float*)d_out;
  for (int l=0; l<LL; ++l) {
    const float* Wz = W_zr + (size_t)l*128*128; const float* bz = b_zr + l*128;
    const float* Wc = W_c  + (size_t)l*128*64;  const float* bc = b_c + l*64;
    const float* Wo = W_out+ (size_t)l*64*64;   const float* bo = b_out + l*64;
    prep_w_kernel<<<64,256,0,stream>>>(Wz, Wc, Wo, Wz_sw, Wc_sw, Wo_sw);
    topk_kernel<<<625,256,0,stream>>>(embs + (size_t)l*NN*DEMB, tki, tkw);
    transpose_kernel<<<dim3((NN+31)/32, CC/32, BT), dim3(32,8), 0, stream>>>(outp, xt);
    edge_agg_kernel<<<dim3(125, BT),256,0,stream>>>(
        (const uint4*)xt, (uint4*)eaggx, eoff, enodes, inv_e);
    conv_x_kernel<<<dim3(313, BT),256,0,stream>>>(
        (const uint4*)xt, (const uint4*)eaggx, noff, nedges, inv_n, tki, tkw, (uint4*)cx);
    for (int t=0; t<TT; ++t) {
      int hz = (t==0) ? 1 : 0;
      if (!hz)
        edge_agg_kernel<<<dim3(125, BB),256,0,stream>>>(
            (const uint4*)hbuf, (uint4*)eaggh, eoff, enodes, inv_e);
      step_zr_kernel<<<dim3(313, BB),256,0,stream>>>(
          (const uint4*)hbuf, (const uint4*)cx, (const uint4*)eaggh, Wz_sw, bz,
          noff, nedges, inv_n, tki, tkw, hbuf, rhbuf, zbuf, t, hz);
      if (!hz)
        edge_agg_kernel<<<dim3(125, BB),256,0,stream>>>(
            (const uint4*)rhbuf, (uint4*)eaggh, eoff, enodes, inv_e);
      step_hy_kernel<<<dim3(313, BB),256,0,stream>>>(
          (const uint4*)rhbuf, (const uint4*)cx, (const uint4*)eaggh, Wc_sw, bc, Wo_sw, bo,
          noff, nedges, inv_n, tki, tkw, zbuf, hbuf, outp, t, hz);
    }
  }
}

// Round 9
// 2588.092 us; speedup vs baseline: 7.1774x; 1.1081x over previous
//
#include <hip/hip_runtime.h>
#include <hip/hip_fp16.h>
#include <cstdio>

#define BB 4
#define TT 12
#define CC 64
#define NN 10000
#define HH 64
#define LL 2
#define NEDGE 2000
#define NNZT 80000
#define KTOP 10
#define DEMB 16
#define BT (BB*TT)

typedef long long ll;
typedef unsigned long long u64;
typedef unsigned int u32;
typedef unsigned short ushort;

typedef short bf16x8 __attribute__((ext_vector_type(8)));
typedef float f32x4 __attribute__((ext_vector_type(4)));

// ---------- fp16 row helpers: 8 channels per uint4 ----------
__device__ __forceinline__ void up8(const uint4 v, float* f) {
  const __half2* p = reinterpret_cast<const __half2*>(&v);
  float2 t0 = __half22float2(p[0]);
  float2 t1 = __half22float2(p[1]);
  float2 t2 = __half22float2(p[2]);
  float2 t3 = __half22float2(p[3]);
  f[0]=t0.x; f[1]=t0.y; f[2]=t1.x; f[3]=t1.y;
  f[4]=t2.x; f[5]=t2.y; f[6]=t3.x; f[7]=t3.y;
}
__device__ __forceinline__ uint4 pk8(const float* f) {
  __half2 h0 = __floats2half2_rn(f[0], f[1]);
  __half2 h1 = __floats2half2_rn(f[2], f[3]);
  __half2 h2 = __floats2half2_rn(f[4], f[5]);
  __half2 h3 = __floats2half2_rn(f[6], f[7]);
  uint4 r;
  r.x = *reinterpret_cast<unsigned*>(&h0);
  r.y = *reinterpret_cast<unsigned*>(&h1);
  r.z = *reinterpret_cast<unsigned*>(&h2);
  r.w = *reinterpret_cast<unsigned*>(&h3);
  return r;
}
__device__ __forceinline__ ushort f2bf(float x) {
  u32 u = __float_as_uint(x);
  u32 r = u + 0x7FFFu + ((u >> 16) & 1u);
  return (ushort)(r >> 16);
}
__device__ __forceinline__ uint4 pk8bf(const float* f) {
  uint4 r;
  r.x = (u32)f2bf(f[0]) | ((u32)f2bf(f[1])<<16);
  r.y = (u32)f2bf(f[2]) | ((u32)f2bf(f[3])<<16);
  r.z = (u32)f2bf(f[4]) | ((u32)f2bf(f[5])<<16);
  r.w = (u32)f2bf(f[6]) | ((u32)f2bf(f[7])<<16);
  return r;
}

// ---------------- graph setup ----------------
__global__ void deg_kernel(const int* __restrict__ nidx, const int* __restrict__ eidx,
                           int* __restrict__ ndeg, int* __restrict__ edeg) {
  int i = blockIdx.x*256 + threadIdx.x;
  if (i < NNZT) { atomicAdd(&ndeg[nidx[i]],1); atomicAdd(&edeg[eidx[i]],1); }
}

__global__ void exscan_kernel(const int* __restrict__ cnt, int* __restrict__ off, int n) {
  __shared__ int part[256];
  int tid = threadIdx.x;
  int chunk = (n + 255)/256;
  int lo = tid*chunk, hi = min(lo+chunk, n);
  int s = 0;
  for (int i=lo; i<hi; ++i) s += cnt[i];
  part[tid]=s; __syncthreads();
  if (tid==0){ int acc=0; for(int i=0;i<256;++i){int v=part[i];part[i]=acc;acc+=v;} off[n]=acc; }
  __syncthreads();
  int acc = part[tid];
  for (int i=lo; i<hi; ++i){ off[i]=acc; acc+=cnt[i]; }
}

__global__ void fill_csr_kernel(const int* __restrict__ nidx, const int* __restrict__ eidx,
                                const int* __restrict__ noff, const int* __restrict__ eoff,
                                int* __restrict__ ncur, int* __restrict__ ecur,
                                int* __restrict__ node_edges, int* __restrict__ edge_nodes) {
  int i = blockIdx.x*256 + threadIdx.x;
  if (i >= NNZT) return;
  int n = nidx[i], e = eidx[i];
  int pn = atomicAdd(&ncur[n],1);
  node_edges[noff[n]+pn] = e;
  int pe = atomicAdd(&ecur[e],1);
  edge_nodes[eoff[e]+pe] = n;
}

__global__ void invdeg_kernel(const int* __restrict__ ndeg, const int* __restrict__ edeg,
                              float* __restrict__ inv_n, float* __restrict__ inv_e) {
  int i = blockIdx.x*256+threadIdx.x;
  if (i < NN) inv_n[i] = 1.0f/fmaxf((float)ndeg[i],1.0f);
  if (i < NEDGE) inv_e[i] = 1.0f/fmaxf((float)edeg[i],1.0f);
}

// ---------------- weight swizzle for MFMA B operands (bf16), both layers ----------------
__global__ void prep_w_kernel(const float* __restrict__ W_zr, const float* __restrict__ W_c,
                              const float* __restrict__ W_o,
                              short* __restrict__ Wz_swb, short* __restrict__ Wc_swb,
                              short* __restrict__ Wo_swb) {
  int l = blockIdx.y;
  const float* Wz = W_zr + (size_t)l*128*128;
  const float* Wc = W_c  + (size_t)l*128*64;
  const float* Wo = W_o  + (size_t)l*64*64;
  short* Wz_sw = Wz_swb + (size_t)l*16384;
  short* Wc_sw = Wc_swb + (size_t)l*8192;
  short* Wo_sw = Wo_swb + (size_t)l*4096;
  int idx = blockIdx.x*256 + threadIdx.x;
  if (idx < 16384) {  // Wz: [8][4][64][8], K=128, N=128
    int i = idx&7, lane = (idx>>3)&63, kk = (idx>>9)&3, tc = idx>>11;
    int k = kk*32 + (lane>>4)*8 + i, col = tc*16 + (lane&15);
    Wz_sw[idx] = (short)f2bf(Wz[k*128+col]);
  }
  if (idx < 8192) {   // Wc: [4][4][64][8], K=128, N=64
    int i = idx&7, lane = (idx>>3)&63, kk = (idx>>9)&3, tc = idx>>11;
    int k = kk*32 + (lane>>4)*8 + i, col = tc*16 + (lane&15);
    Wc_sw[idx] = (short)f2bf(Wc[k*64+col]);
  }
  if (idx < 4096) {   // Wo: [4][2][64][8], K=64, N=64
    int i = idx&7, lane = (idx>>3)&63, kk = (idx>>9)&1, tc = idx>>10;
    int k = kk*32 + (lane>>4)*8 + i, col = tc*16 + (lane&15);
    Wo_sw[idx] = (short)f2bf(Wo[k*64+col]);
  }
}

// ---------------- top-k: wave-uniform threshold + buffered bitonic reselect ----------------
__device__ __forceinline__ u64 sortstep(u64 X, int j, bool dir, int lane) {
  u64 p = __shfl_xor(X, j);
  bool lower = ((lane & j) == 0);
  bool keep_min = (dir == lower);
  bool xlt = (X < p);
  u64 mn = xlt ? X : p;
  u64 mx = xlt ? p : X;
  return keep_min ? mn : mx;
}

__device__ __forceinline__ void reselect(u64* bq, u64& thr, int& cnt, int lane) {
  int tot = 10 + cnt;                       // <= 113 < 128
  u64 A = (lane < tot)      ? bq[lane]      : 0ull;
  u64 B = (lane + 64 < tot) ? bq[lane + 64] : 0ull;
  for (int k = 2; k <= 32; k <<= 1) {
    for (int j = k >> 1; j >= 1; j >>= 1) {
      bool dir = ((lane & k) == 0);
      A = sortstep(A, j, dir, lane);
      B = sortstep(B, j, dir, lane);
    }
  }
  for (int j = 32; j >= 1; j >>= 1) {
    A = sortstep(A, j, true,  lane);
    B = sortstep(B, j, false, lane);
  }
  {
    bool lt = (A < B);
    u64 mn = lt ? A : B, mx = lt ? B : A;
    A = mn; B = mx;
  }
  for (int j = 32; j >= 1; j >>= 1) {
    A = sortstep(A, j, true, lane);
    B = sortstep(B, j, true, lane);
  }
  if (lane >= 54) bq[63 - lane] = B;
  thr = __shfl(B, 54);
  cnt = 0;
}

// grid (625, 2): blockIdx.y = layer
__global__ void __launch_bounds__(256) topk_kernel(const float* __restrict__ embs,
                                                   int* __restrict__ tk_idx_b,
                                                   float* __restrict__ tk_w_b) {
  __shared__ u64 buf[16][128];
  const float* E = embs + (ll)blockIdx.y*NN*DEMB;
  int* tk_idx = tk_idx_b + (ll)blockIdx.y*NN*KTOP;
  float* tk_w = tk_w_b + (ll)blockIdx.y*NN*KTOP;
  int tid = threadIdx.x;
  int wv = tid >> 6, lane = tid & 63;
  int qbase = blockIdx.x*16 + wv*4;         // 625*16 = 10000 exactly
  const float4* E4 = (const float4*)E;
  float4 q[4][4];
  #pragma unroll
  for (int u=0;u<4;++u) {
    int n = qbase + u;
    #pragma unroll
    for (int j=0;j<4;++j) q[u][j] = E4[(ll)n*4 + j];
  }
  u64 thr[4] = {0,0,0,0};
  int cnt[4] = {0,0,0,0};
  buf[tid>>4][tid&15] = 0ull;
  for (int cb=0; cb<NN; cb+=64) {
    int cand = cb + lane;
    bool valid = (cand < NN);
    int ca = valid ? cand : 0;
    float4 a0 = E4[(ll)ca*4], a1 = E4[(ll)ca*4+1], a2 = E4[(ll)ca*4+2], a3 = E4[(ll)ca*4+3];
    u64 low = (u64)(0x00FFFFFFu - (unsigned)cand);
    u64 key[4];
    #pragma unroll
    for (int u=0;u<4;++u) {
      float dot = q[u][0].x*a0.x + q[u][0].y*a0.y + q[u][0].z*a0.z + q[u][0].w*a0.w
                + q[u][1].x*a1.x + q[u][1].y*a1.y + q[u][1].z*a1.z + q[u][1].w*a1.w
                + q[u][2].x*a2.x + q[u][2].y*a2.y + q[u][2].z*a2.z + q[u][2].w*a2.w
                + q[u][3].x*a3.x + q[u][3].y*a3.y + q[u][3].z*a3.z + q[u][3].w*a3.w;
      float s = fmaxf(dot, 0.f);
      u64 kk = ((u64)__float_as_uint(s) << 32) | low;
      key[u] = valid ? kk : 0ull;
    }
    #pragma unroll
    for (int u=0;u<4;++u) {
      u64 mask = __ballot(key[u] > thr[u]);
      if (mask) {
        if (key[u] > thr[u]) {
          int myofs = (int)__popcll(mask & ((1ull<<lane)-1ull));
          buf[wv*4+u][10 + cnt[u] + myofs] = key[u];
        }
        cnt[u] += (int)__popcll(mask);
        if (cnt[u] >= 40) reselect(&buf[wv*4+u][0], thr[u], cnt[u], lane);
      }
    }
  }
  #pragma unroll
  for (int u=0;u<4;++u) {
    u64* bq = &buf[wv*4+u][0];
    if (cnt[u] > 0) reselect(bq, thr[u], cnt[u], lane);
    u64 k10 = (lane < 10) ? bq[lane] : 0ull;
    float v = __uint_as_float((unsigned)(k10 >> 32));
    int idx = 0x00FFFFFF - (int)(k10 & 0xFFFFFFFFull);
    float v0 = __shfl(v, 0);
    float e = (lane < 10) ? expf(v - v0) : 0.f;
    float s = e;
    for (int o=1;o<16;o<<=1) s += __shfl_xor(s, o);
    if (lane < 10) {
      int n = qbase + u;
      tk_w[n*KTOP + lane] = e / s;
      tk_idx[n*KTOP + lane] = idx;
    }
  }
}

// ---------------- (B,T,C,N) fp32 -> (B*T, N, C) fp16 transpose ----------------
__global__ void transpose_kernel(const float* __restrict__ src, __half* __restrict__ dst) {
  __shared__ float tile[32][33];
  int bt = blockIdx.z;
  int n0 = blockIdx.x*32, c0 = blockIdx.y*32;
  for (int i=threadIdx.y; i<32; i+=8) {
    int c = c0+i, nn = n0+threadIdx.x;
    tile[i][threadIdx.x] = (nn<NN)? src[((ll)bt*CC + c)*NN + nn] : 0.0f;
  }
  __syncthreads();
  for (int i=threadIdx.y; i<32; i+=8) {
    int nn = n0+i, c = c0+threadIdx.x;
    if (nn<NN) dst[((ll)bt*NN+nn)*64 + c] = __float2half_rn(tile[threadIdx.x][i]);
  }
}

// ---------------- edge aggregation (fp16 rows, LDS-staged index lists) ----------------
__global__ void __launch_bounds__(256) edge_agg_kernel(
    const uint4* __restrict__ f8, uint4* __restrict__ eagg8,
    const int* __restrict__ eoff, const int* __restrict__ enodes,
    const float* __restrict__ inv_e) {
  __shared__ int en_s[1088];
  __shared__ int jo_s[17];
  int tid = threadIdx.x;
  int e0 = blockIdx.x*16;     // grid.x=125 -> e0+15 <= 1999 always valid
  int s = blockIdx.y;
  if (tid < 17) jo_s[tid] = eoff[e0 + tid];
  __syncthreads();
  int jb0 = jo_s[0], cnt = jo_s[16] - jb0;
  bool stg = (cnt <= 1088);
  if (stg) for (int i = tid; i < cnt; i += 256) en_s[i] = enodes[jb0 + i];
  __syncthreads();
  int esub = tid>>4;
  int e = e0 + esub;
  int hsel = (tid>>3)&1;
  int lane8 = tid&7;
  int j0 = jo_s[esub] - jb0, j1 = jo_s[esub+1] - jb0;
  const uint4* fb = f8 + (ll)s*NN*8;
  float acc[8] = {0,0,0,0,0,0,0,0};
  for (int j = j0 + hsel; j < j1; j += 2) {
    int node = stg ? en_s[j] : enodes[jb0+j];
    float t[8]; up8(fb[(ll)node*8 + lane8], t);
    #pragma unroll
    for (int q=0;q<8;++q) acc[q] += t[q];
  }
  #pragma unroll
  for (int q=0;q<8;++q) acc[q] += __shfl_xor(acc[q], 8);
  if (hsel == 0) {
    float sc = inv_e[e];
    #pragma unroll
    for (int q=0;q<8;++q) acc[q] *= sc;
    eagg8[((ll)s*NEDGE+e)*8 + lane8] = pk8(acc);
  }
}

// ---------------- conv applied to x for all (b,t) ----------------
__global__ void __launch_bounds__(256) conv_x_kernel(
    const uint4* __restrict__ xt8, const uint4* __restrict__ eagg8,
    const int* __restrict__ noff, const int* __restrict__ nedges,
    const float* __restrict__ inv_n,
    const int* __restrict__ tk_idx, const float* __restrict__ tk_w,
    uint4* __restrict__ cx8) {
  __shared__ int tki_s[32][KTOP];
  __shared__ float tkw_s[32][KTOP];
  __shared__ int ne_s[640];
  __shared__ int no_s[33];
  int tid = threadIdx.x; int s = blockIdx.y; int n0 = blockIdx.x*32;
  if (tid < 33) no_s[tid] = noff[min(n0 + tid, NN)];
  for (int i=tid; i<32*KTOP; i+=256) {
    int r=i/KTOP, k=i%KTOP; int n = n0+r;
    tki_s[r][k] = (n<NN)? tk_idx[n*KTOP+k] : 0;
    tkw_s[r][k] = (n<NN)? tk_w[n*KTOP+k] : 0.f;
  }
  __syncthreads();
  int jb0 = no_s[0], cnt = no_s[32] - jb0;
  bool stg = (cnt <= 640);
  if (stg) for (int i=tid; i<cnt; i+=256) ne_s[i] = nedges[jb0+i];
  __syncthreads();
  int row = tid>>3, lane8 = tid&7;
  int n = n0 + row;
  if (n >= NN) return;
  float stv[8] = {0,0,0,0,0,0,0,0};
  const uint4* eb = eagg8 + (ll)s*NEDGE*8;
  int j0 = no_s[row] - jb0, j1 = no_s[row+1] - jb0;
  for (int j=j0;j<j1;++j) {
    int eidx = stg ? ne_s[j] : nedges[jb0+j];
    float t[8]; up8(eb[(ll)eidx*8 + lane8], t);
    #pragma unroll
    for (int q=0;q<8;++q) stv[q] += t[q];
  }
  float sc = 0.5f*inv_n[n];
  float adv[8] = {0,0,0,0,0,0,0,0};
  const uint4* xb = xt8 + (ll)s*NN*8;
  #pragma unroll
  for (int k=0;k<KTOP;++k) {
    float w = tkw_s[row][k];
    float t[8]; up8(xb[(ll)tki_s[row][k]*8 + lane8], t);
    #pragma unroll
    for (int q=0;q<8;++q) adv[q] += w*t[q];
  }
  float r8[8];
  #pragma unroll
  for (int q=0;q<8;++q) r8[q] = sc*stv[q] + 0.5f*adv[q];
  cx8[((ll)s*NN+n)*8+lane8] = pk8(r8);
}

// ---------------- fused t=0 step: h=0 -> no cross-node dependency ----------------
__global__ void __launch_bounds__(256) step0_kernel(
    const uint4* __restrict__ cx8,
    const short* __restrict__ Wz_sw, const float* __restrict__ bz,
    const short* __restrict__ Wc_sw, const float* __restrict__ bc,
    const short* __restrict__ Wo_sw, const float* __restrict__ bo,
    __half* __restrict__ h, float* __restrict__ out) {
  __shared__ __align__(16) short in_bf[32][72];
  __shared__ __align__(16) short hn[32][72];
  __shared__ __align__(16) float yt[64][36];
  int tid = threadIdx.x;
  int b = blockIdx.y; int n0 = blockIdx.x*32;
  int bt = b*TT;   // t = 0
  {
    int row = tid>>3, lane8 = tid&7;
    int n = n0 + row;
    float cxv[8] = {0,0,0,0,0,0,0,0};
    if (n < NN) up8(cx8[((ll)bt*NN + n)*8 + lane8], cxv);
    *(uint4*)&in_bf[row][lane8*8] = pk8bf(cxv);
  }
  __syncthreads();
  int wv = tid>>6, lane = tid&63;
  int m = lane&15, g = lane>>4;
  // z = sigma(cx*Wz[0:64, 0:64]), c = tanh(cx*Wc[0:64,:]); 8 tiles each, K=64 (kk 0..1)
  #pragma unroll
  for (int q=0;q<2;++q) {
    int T = wv + 4*q;
    int tr = T>>2, tc = T&3;
    f32x4 az = {0.f,0.f,0.f,0.f};
    f32x4 ac = {0.f,0.f,0.f,0.f};
    #pragma unroll
    for (int kk=0;kk<2;++kk) {
      bf16x8 a = *(const bf16x8*)&in_bf[tr*16 + m][kk*32 + g*8];
      bf16x8 bwz = *(const bf16x8*)&Wz_sw[((tc*4+kk)*64 + lane)*8];
      bf16x8 bwc = *(const bf16x8*)&Wc_sw[((tc*4+kk)*64 + lane)*8];
      az = __builtin_amdgcn_mfma_f32_16x16x32_bf16(a, bwz, az, 0, 0, 0);
      ac = __builtin_amdgcn_mfma_f32_16x16x32_bf16(a, bwc, ac, 0, 0, 0);
    }
    int col = tc*16 + m;
    float bzv = bz[col], bcv = bc[col];
    #pragma unroll
    for (int r=0;r<4;++r) {
      int row = tr*16 + g*4 + r;
      int n = n0 + row;
      float z = 1.0f/(1.0f+expf(-(az[r]+bzv)));
      float cval = tanhf(ac[r]+bcv);
      float hnew = (1.0f-z)*cval;
      if (n < NN) h[((ll)b*NN+n)*64+col] = __float2half_rn(hnew);
      hn[row][col] = (short)f2bf(hnew);
    }
  }
  __syncthreads();
  // y = hn * Wo + bo
  #pragma unroll
  for (int q=0;q<2;++q) {
    int T = wv + 4*q;
    int tr = T>>2, tc = T&3;
    f32x4 acc = {0.f,0.f,0.f,0.f};
    #pragma unroll
    for (int kk=0;kk<2;++kk) {
      bf16x8 a = *(const bf16x8*)&hn[tr*16 + m][kk*32 + g*8];
      bf16x8 bw = *(const bf16x8*)&Wo_sw[((tc*2+kk)*64 + lane)*8];
      acc = __builtin_amdgcn_mfma_f32_16x16x32_bf16(a, bw, acc, 0, 0, 0);
    }
    int col = tc*16 + m;
    float bias = bo[col];
    #pragma unroll
    for (int r=0;r<4;++r) {
      int row = tr*16 + g*4 + r;
      yt[col][row] = acc[r] + bias;
    }
  }
  __syncthreads();
  #pragma unroll
  for (int kk=0;kk<2;++kk) {
    int slot = tid + kk*256;
    int col = slot>>3, q = slot&7;
    int n = n0 + q*4;
    if (n < NN) {
      float4 y = *(const float4*)&yt[col][q*4];
      float4* dst = (float4*)&out[((ll)bt*64+col)*NN + n];
      float4 cur = *dst;
      cur.x += y.x; cur.y += y.y; cur.z += y.z; cur.w += y.w;
      *dst = cur;
    }
  }
}

// ---------------- GRU step kernel 1: gates z,r (MFMA, t>=1) ----------------
__global__ void __launch_bounds__(256) step_zr_kernel(
    const uint4* __restrict__ h8, const uint4* __restrict__ cx8,
    const uint4* __restrict__ eagg8,
    const short* __restrict__ Wz_sw, const float* __restrict__ bz,
    const int* __restrict__ noff, const int* __restrict__ nedges,
    const float* __restrict__ inv_n,
    const int* __restrict__ tk_idx, const float* __restrict__ tk_w,
    const __half* __restrict__ hs,
    __half* __restrict__ rh, __half* __restrict__ zout, int t) {
  __shared__ __align__(16) short in_bf[32][136];
  __shared__ int tki_s[32][KTOP];
  __shared__ float tkw_s[32][KTOP];
  __shared__ int ne_s[640];
  __shared__ int no_s[33];
  int tid = threadIdx.x;
  int b = blockIdx.y; int n0 = blockIdx.x*32;
  int bt = b*TT + t;
  if (tid < 33) no_s[tid] = noff[min(n0 + tid, NN)];
  for (int i=tid; i<32*KTOP; i+=256) {
    int r=i/KTOP, k=i%KTOP; int n=n0+r;
    tki_s[r][k] = (n<NN)? tk_idx[n*KTOP+k] : 0;
    tkw_s[r][k] = (n<NN)? tk_w[n*KTOP+k] : 0.f;
  }
  __syncthreads();
  int jb0 = no_s[0], ecnt = no_s[32] - jb0;
  bool stg = (ecnt <= 640);
  if (stg) for (int i=tid; i<ecnt; i+=256) ne_s[i] = nedges[jb0+i];
  __syncthreads();
  {
    int row = tid>>3, lane8 = tid&7;
    int n = n0 + row;
    float cxv[8] = {0,0,0,0,0,0,0,0};
    float chv[8] = {0,0,0,0,0,0,0,0};
    if (n < NN) {
      up8(cx8[((ll)bt*NN + n)*8 + lane8], cxv);
      float stv[8] = {0,0,0,0,0,0,0,0};
      int j0 = no_s[row] - jb0, j1 = no_s[row+1] - jb0;
      const uint4* eb = eagg8 + (ll)b*NEDGE*8;
      for (int j=j0;j<j1;++j) {
        int eidx = stg ? ne_s[j] : nedges[jb0+j];
        float t8[8]; up8(eb[(ll)eidx*8 + lane8], t8);
        #pragma unroll
        for (int q=0;q<8;++q) stv[q] += t8[q];
      }
      float sc = 0.5f*inv_n[n];
      const uint4* hb = h8 + (ll)b*NN*8;
      float adv[8] = {0,0,0,0,0,0,0,0};
      #pragma unroll
      for (int k=0;k<KTOP;++k) {
        float w = tkw_s[row][k];
        float t8[8]; up8(hb[(ll)tki_s[row][k]*8 + lane8], t8);
        #pragma unroll
        for (int q=0;q<8;++q) adv[q] += w*t8[q];
      }
      #pragma unroll
      for (int q=0;q<8;++q) chv[q] = sc*stv[q] + 0.5f*adv[q];
    }
    *(uint4*)&in_bf[row][lane8*8]    = pk8bf(cxv);
    *(uint4*)&in_bf[row][64+lane8*8] = pk8bf(chv);
  }
  __syncthreads();
  // MFMA GEMM: C[32][128] = in_bf[32][128] x Wz[128][128]; 16 tiles of 16x16
  int wv = tid>>6, lane = tid&63;
  int m = lane&15, g = lane>>4;
  #pragma unroll
  for (int q=0;q<4;++q) {
    int T = wv*4 + q;
    int tr = T>>3, tc = T&7;
    f32x4 acc = {0.f,0.f,0.f,0.f};
    #pragma unroll
    for (int kk=0;kk<4;++kk) {
      bf16x8 a = *(const bf16x8*)&in_bf[tr*16 + m][kk*32 + g*8];
      bf16x8 bf = *(const bf16x8*)&Wz_sw[((tc*4+kk)*64 + lane)*8];
      acc = __builtin_amdgcn_mfma_f32_16x16x32_bf16(a, bf, acc, 0, 0, 0);
    }
    int col = tc*16 + m;
    float bias = bz[col];
    #pragma unroll
    for (int r=0;r<4;++r) {
      int row = tr*16 + g*4 + r;
      int n = n0 + row;
      if (n < NN) {
        float v = 1.0f/(1.0f+expf(-(acc[r]+bias)));
        if (col < 64) zout[((ll)b*NN+n)*64+col] = __float2half_rn(v);
        else {
          int c = col-64;
          float hv = __half2float(hs[((ll)b*NN+n)*64+c]);
          rh[((ll)b*NN+n)*64+c] = __float2half_rn(v*hv);
        }
      }
    }
  }
}

// ---------------- GRU step kernel 2: candidate, h update, output (MFMA, t>=1) ----------------
__global__ void __launch_bounds__(256) step_hy_kernel(
    const uint4* __restrict__ rh8, const uint4* __restrict__ cx8,
    const uint4* __restrict__ eagg8,
    const short* __restrict__ Wc_sw, const float* __restrict__ bc,
    const short* __restrict__ Wo_sw, const float* __restrict__ bo,
    const int* __restrict__ noff, const int* __restrict__ nedges,
    const float* __restrict__ inv_n,
    const int* __restrict__ tk_idx, const float* __restrict__ tk_w,
    const __half* __restrict__ zbuf, __half* __restrict__ h,
    float* __restrict__ out, int t) {
  __shared__ __align__(16) short in_bf[32][136];
  __shared__ __align__(16) short hn[32][72];
  __shared__ __align__(16) float yt[64][36];
  __shared__ int tki_s[32][KTOP];
  __shared__ float tkw_s[32][KTOP];
  __shared__ int ne_s[640];
  __shared__ int no_s[33];
  int tid = threadIdx.x;
  int b = blockIdx.y; int n0 = blockIdx.x*32;
  int bt = b*TT + t;
  if (tid < 33) no_s[tid] = noff[min(n0 + tid, NN)];
  for (int i=tid; i<32*KTOP; i+=256) {
    int r=i/KTOP, k=i%KTOP; int n=n0+r;
    tki_s[r][k] = (n<NN)? tk_idx[n*KTOP+k] : 0;
    tkw_s[r][k] = (n<NN)? tk_w[n*KTOP+k] : 0.f;
  }
  __syncthreads();
  int jb0 = no_s[0], ecnt = no_s[32] - jb0;
  bool stg = (ecnt <= 640);
  if (stg) for (int i=tid; i<ecnt; i+=256) ne_s[i] = nedges[jb0+i];
  __syncthreads();
  {
    int row = tid>>3, lane8 = tid&7;
    int n = n0 + row;
    float cxv[8] = {0,0,0,0,0,0,0,0};
    float chv[8] = {0,0,0,0,0,0,0,0};
    if (n < NN) {
      up8(cx8[((ll)bt*NN + n)*8 + lane8], cxv);
      float stv[8] = {0,0,0,0,0,0,0,0};
      int j0 = no_s[row] - jb0, j1 = no_s[row+1] - jb0;
      const uint4* eb = eagg8 + (ll)b*NEDGE*8;
      for (int j=j0;j<j1;++j) {
        int eidx = stg ? ne_s[j] : nedges[jb0+j];
        float t8[8]; up8(eb[(ll)eidx*8 + lane8], t8);
        #pragma unroll
        for (int q=0;q<8;++q) stv[q] += t8[q];
      }
      float sc = 0.5f*inv_n[n];
      const uint4* rb = rh8 + (ll)b*NN*8;
      float adv[8] = {0,0,0,0,0,0,0,0};
      #pragma unroll
      for (int k=0;k<KTOP;++k) {
        float w = tkw_s[row][k];
        float t8[8]; up8(rb[(ll)tki_s[row][k]*8 + lane8], t8);
        #pragma unroll
        for (int q=0;q<8;++q) adv[q] += w*t8[q];
      }
      #pragma unroll
      for (int q=0;q<8;++q) chv[q] = sc*stv[q] + 0.5f*adv[q];
    }
    *(uint4*)&in_bf[row][lane8*8]    = pk8bf(cxv);
    *(uint4*)&in_bf[row][64+lane8*8] = pk8bf(chv);
  }
  __syncthreads();
  int wv = tid>>6, lane = tid&63;
  int m = lane&15, g = lane>>4;
  // GEMM1: C[32][64] = in_bf[32][128] x Wc[128][64]; 8 tiles
  #pragma unroll
  for (int q=0;q<2;++q) {
    int T = wv + 4*q;
    int tr = T>>2, tc = T&3;
    f32x4 acc = {0.f,0.f,0.f,0.f};
    #pragma unroll
    for (int kk=0;kk<4;++kk) {
      bf16x8 a = *(const bf16x8*)&in_bf[tr*16 + m][kk*32 + g*8];
      bf16x8 bf = *(const bf16x8*)&Wc_sw[((tc*4+kk)*64 + lane)*8];
      acc = __builtin_amdgcn_mfma_f32_16x16x32_bf16(a, bf, acc, 0, 0, 0);
    }
    int col = tc*16 + m;
    float bias = bc[col];
    #pragma unroll
    for (int r=0;r<4;++r) {
      int row = tr*16 + g*4 + r;
      int n = n0 + row;
      float hnew = 0.0f;
      if (n < NN) {
        float cval = tanhf(acc[r]+bias);
        float z = __half2float(zbuf[((ll)b*NN+n)*64+col]);
        float hv = __half2float(h[((ll)b*NN+n)*64+col]);
        hnew = z*hv + (1.0f-z)*cval;
        h[((ll)b*NN+n)*64+col] = __float2half_rn(hnew);
      }
      hn[row][col] = (short)f2bf(hnew);
    }
  }
  __syncthreads();
  // GEMM2: y[32][64] = hn[32][64] x Wo[64][64]; 8 tiles
  #pragma unroll
  for (int q=0;q<2;++q) {
    int T = wv + 4*q;
    int tr = T>>2, tc = T&3;
    f32x4 acc = {0.f,0.f,0.f,0.f};
    #pragma unroll
    for (int kk=0;kk<2;++kk) {
      bf16x8 a = *(const bf16x8*)&hn[tr*16 + m][kk*32 + g*8];
      bf16x8 bf = *(const bf16x8*)&Wo_sw[((tc*2+kk)*64 + lane)*8];
      acc = __builtin_amdgcn_mfma_f32_16x16x32_bf16(a, bf, acc, 0, 0, 0);
    }
    int col = tc*16 + m;
    float bias = bo[col];
    #pragma unroll
    for (int r=0;r<4;++r) {
      int row = tr*16 + g*4 + r;
      yt[col][row] = acc[r] + bias;
    }
  }
  __syncthreads();
  #pragma unroll
  for (int kk=0;kk<2;++kk) {
    int slot = tid + kk*256;
    int col = slot>>3, q = slot&7;
    int n = n0 + q*4;
    if (n < NN) {
      float4 y = *(const float4*)&yt[col][q*4];
      float4* dst = (float4*)&out[((ll)bt*64+col)*NN + n];
      float4 cur = *dst;
      cur.x += y.x; cur.y += y.y; cur.z += y.z; cur.w += y.w;
      *dst = cur;
    }
  }
}

extern "C" void kernel_launch(void* const* d_in, const int* in_sizes, int n_in,
                              void* d_out, int out_size, void* d_ws, size_t ws_size,
                              hipStream_t stream) {
  const float* x    = (const float*)d_in[0];
  const int*  hidx  = (const int*)d_in[1];
  const float* embs = (const float*)d_in[2];
  const float* W_zr = (const float*)d_in[3];
  const float* b_zr = (const float*)d_in[4];
  const float* W_c  = (const float*)d_in[5];
  const float* b_c  = (const float*)d_in[6];
  const float* W_out= (const float*)d_in[7];
  const float* b_out= (const float*)d_in[8];
  const int* node_idx = hidx;
  const int* edge_idx = hidx + NNZT;

  char* ws = (char*)d_ws;
  size_t off = 0;
  auto alloc = [&](size_t bytes) -> void* {
    void* p = ws + off; off += (bytes + 255) & ~(size_t)255; return p;
  };
  __half* xt    = (__half*)alloc((size_t)BT*NN*64*2);
  __half* cx    = (__half*)alloc((size_t)BT*NN*64*2);
  __half* eaggx = (__half*)alloc((size_t)BT*NEDGE*64*2);
  __half* eaggh = (__half*)alloc((size_t)BB*NEDGE*64*2);
  __half* hbuf  = (__half*)alloc((size_t)BB*NN*64*2);
  __half* rhbuf = (__half*)alloc((size_t)BB*NN*64*2);
  __half* zbuf  = (__half*)alloc((size_t)BB*NN*64*2);
  short* Wz_sw = (short*)alloc((size_t)LL*16384*2);
  short* Wc_sw = (short*)alloc((size_t)LL*8192*2);
  short* Wo_sw = (short*)alloc((size_t)LL*4096*2);
  float* tkw   = (float*)alloc((size_t)LL*NN*KTOP*4);
  float* inv_e = (float*)alloc(NEDGE*4);
  float* inv_n = (float*)alloc(NN*4);
  int* tki     = (int*)alloc((size_t)LL*NN*KTOP*4);
  int* ndeg    = (int*)alloc(NN*4);
  int* edeg    = (int*)alloc(NEDGE*4);
  int* noff    = (int*)alloc((NN+1)*4);
  int* eoff    = (int*)alloc((NEDGE+1)*4);
  int* ncur    = (int*)alloc(NN*4);
  int* ecur    = (int*)alloc(NEDGE*4);
  int* nedges  = (int*)alloc(NNZT*4);
  int* enodes  = (int*)alloc(NNZT*4);
  if (off > ws_size) {
    fprintf(stderr, "kernel_launch: ws too small, need %zu have %zu\n", off, ws_size);
    return;
  }

  // out starts as x (residual base)
  hipMemcpyAsync(d_out, x, (size_t)BB*TT*CC*NN*4, hipMemcpyDeviceToDevice, stream);

  // graph structure (once)
  hipMemsetAsync(ndeg, 0, NN*4, stream);
  hipMemsetAsync(edeg, 0, NEDGE*4, stream);
  hipMemsetAsync(ncur, 0, NN*4, stream);
  hipMemsetAsync(ecur, 0, NEDGE*4, stream);
  deg_kernel<<<(NNZT+255)/256,256,0,stream>>>(node_idx, edge_idx, ndeg, edeg);
  exscan_kernel<<<1,256,0,stream>>>(ndeg, noff, NN);
  exscan_kernel<<<1,256,0,stream>>>(edeg, eoff, NEDGE);
  fill_csr_kernel<<<(NNZT+255)/256,256,0,stream>>>(node_idx, edge_idx, noff, eoff,
                                                   ncur, ecur, nedges, enodes);
  invdeg_kernel<<<(NN+255)/256,256,0,stream>>>(ndeg, edeg, inv_n, inv_e);

  // both layers' weight swizzle + top-k upfront
  prep_w_kernel<<<dim3(64,LL),256,0,stream>>>(W_zr, W_c, W_out, Wz_sw, Wc_sw, Wo_sw);
  topk_kernel<<<dim3(625,LL),256,0,stream>>>(embs, tki, tkw);

  float* outp = (float*)d_out;
  for (int l=0; l<LL; ++l) {
    const short* Wzs = Wz_sw + (size_t)l*16384;
    const short* Wcs = Wc_sw + (size_t)l*8192;
    const short* Wos = Wo_sw + (size_t)l*4096;
    const float* bz = b_zr + l*128;
    const float* bc = b_c + l*64;
    const float* bo = b_out + l*64;
    const int* tkil = tki + (size_t)l*NN*KTOP;
    const float* tkwl = tkw + (size_t)l*NN*KTOP;
    transpose_kernel<<<dim3((NN+31)/32, CC/32, BT), dim3(32,8), 0, stream>>>(outp, xt);
    edge_agg_kernel<<<dim3(125, BT),256,0,stream>>>(
        (const uint4*)xt, (uint4*)eaggx, eoff, enodes, inv_e);
    conv_x_kernel<<<dim3(313, BT),256,0,stream>>>(
        (const uint4*)xt, (const uint4*)eaggx, noff, nedges, inv_n, tkil, tkwl, (uint4*)cx);
    // t = 0 fused (h=0)
    step0_kernel<<<dim3(313, BB),256,0,stream>>>(
        (const uint4*)cx, Wzs, bz, Wcs, bc, Wos, bo, hbuf, outp);
    for (int t=1; t<TT; ++t) {
      edge_agg_kernel<<<dim3(125, BB),256,0,stream>>>(
          (const uint4*)hbuf, (uint4*)eaggh, eoff, enodes, inv_e);
      step_zr_kernel<<<dim3(313, BB),256,0,stream>>>(
          (const uint4*)hbuf, (const uint4*)cx, (const uint4*)eaggh, Wzs, bz,
          noff, nedges, inv_n, tkil, tkwl, hbuf, rhbuf, zbuf, t);
      edge_agg_kernel<<<dim3(125, BB),256,0,stream>>>(
          (const uint4*)rhbuf, (uint4*)eaggh, eoff, enodes, inv_e);
      step_hy_kernel<<<dim3(313, BB),256,0,stream>>>(
          (const uint4*)rhbuf, (const uint4*)cx, (const uint4*)eaggh, Wcs, bc, Wos, bo,
          noff, nedges, inv_n, tkil, tkwl, zbuf, hbuf, outp, t);
    }
  }
}